// Round 2
// baseline (92100.653 us; speedup 1.0000x reference)
//
#include <hip/hip_runtime.h>

#define HID 1024
#define FEAT 128
#define BAT 128
#define NSAMP 96
#define NPRED 8
#define GD 4096            // 4*HID
#define MB (NSAMP * BAT)   // 12288
#define SLOT ((size_t)BAT * HID)  // 131072

typedef unsigned short u16;
typedef short bf16x8 __attribute__((ext_vector_type(8)));
typedef float f32x4 __attribute__((ext_vector_type(4)));

__device__ inline u16 f2bf(float f) {
    unsigned u = __float_as_uint(f);
    u += 0x7FFFu + ((u >> 16) & 1u);
    return (u16)(u >> 16);
}
__device__ inline float bf2f(u16 h) { return __uint_as_float(((unsigned)h) << 16); }
__device__ inline float fsig(float x) { return 1.0f / (1.0f + __expf(-x)); }
__device__ inline float ftanh(float x) { return 1.0f - 2.0f / (__expf(2.0f * x) + 1.0f); }

#define BK 32
#define LDSS 40  // LDS row stride in shorts (32 + 8 pad)

// C[M,N] = A1[M,K1]*B1[N,K1]^T + A2[M,K2]*B2[N,K2]^T + bias, tile 128x128.
// mode 0: LSTM epilogue (gate-interleaved cols: col = 4*unit + gate{i,f,g,o})
// mode 1: plain -> lin_out[M][128] (bf16)
__global__ __launch_bounds__(256, 2) void gemm_lstm(
    const void* A1, int a1f32, int lda1, const u16* __restrict__ B1, int K1,
    const u16* A2, int lda2, const u16* __restrict__ B2, int K2,
    const float* __restrict__ bias,
    const void* c_in, int cin_f32,
    float* cout_f, u16* cout_b,
    u16* h_out, float* hf_out,
    u16* lin_out, int mode)
{
    __shared__ u16 sA[128 * LDSS];
    __shared__ u16 sB[128 * LDSS];
    __shared__ float sG[32][132];

    const int tid = threadIdx.x;
    const int tn = blockIdx.x, tm = blockIdx.y;
    const int wave = tid >> 6, lane = tid & 63;
    const int wm = wave >> 1, wn = wave & 1;
    const int quad = lane >> 4, lc = lane & 15;

    f32x4 acc[4][4];
#pragma unroll
    for (int j = 0; j < 4; ++j) {
        float bv = bias[tn * 128 + wn * 64 + j * 16 + lc];
        f32x4 bvv = {bv, bv, bv, bv};
#pragma unroll
        for (int i = 0; i < 4; ++i) acc[i][j] = bvv;
    }

    for (int seg = 0; seg < 2; ++seg) {
        const void* Ap = seg ? (const void*)A2 : A1;
        const u16* Bp = seg ? B2 : B1;
        const int K = seg ? K2 : K1;
        const int lda = seg ? lda2 : lda1;
        const int af32 = seg ? 0 : a1f32;
        if (K == 0) continue;
        for (int k0 = 0; k0 < K; k0 += BK) {
            if (af32) {
                const float* Af = (const float*)Ap + (size_t)tm * 128 * lda + k0;
#pragma unroll
                for (int it = 0; it < 4; ++it) {
                    int r = it * 32 + (tid >> 3);
                    int c = (tid & 7) * 4;
                    float4 v = *(const float4*)(Af + (size_t)r * lda + c);
                    ushort4 pk = make_ushort4(f2bf(v.x), f2bf(v.y), f2bf(v.z), f2bf(v.w));
                    *(ushort4*)&sA[r * LDSS + c] = pk;
                }
            } else {
                const u16* Ab = (const u16*)Ap + (size_t)tm * 128 * lda + k0;
#pragma unroll
                for (int it = 0; it < 2; ++it) {
                    int r = it * 64 + (tid >> 2);
                    int c = (tid & 3) * 8;
                    uint4 v = *(const uint4*)(Ab + (size_t)r * lda + c);
                    *(uint4*)&sA[r * LDSS + c] = v;
                }
            }
            {
                const u16* Bb = B1 + (size_t)tn * 128 * K + k0;  // placeholder fix below
                (void)Bb;
            }
            {
                const u16* Bb = Bp + (size_t)tn * 128 * K + k0;
#pragma unroll
                for (int it = 0; it < 2; ++it) {
                    int r = it * 64 + (tid >> 2);
                    int c = (tid & 3) * 8;
                    uint4 v = *(const uint4*)(Bb + (size_t)r * K + c);
                    *(uint4*)&sB[r * LDSS + c] = v;
                }
            }
            __syncthreads();
            bf16x8 aF[4], bF[4];
#pragma unroll
            for (int i = 0; i < 4; ++i)
                aF[i] = *(const bf16x8*)&sA[(wm * 64 + i * 16 + lc) * LDSS + quad * 8];
#pragma unroll
            for (int j = 0; j < 4; ++j)
                bF[j] = *(const bf16x8*)&sB[(wn * 64 + j * 16 + lc) * LDSS + quad * 8];
#pragma unroll
            for (int i = 0; i < 4; ++i)
#pragma unroll
                for (int j = 0; j < 4; ++j)
                    acc[i][j] = __builtin_amdgcn_mfma_f32_16x16x32_bf16(aF[i], bF[j], acc[i][j], 0, 0, 0);
            __syncthreads();
        }
    }

    if (mode == 0) {
#pragma unroll 1
        for (int i = 0; i < 4; ++i) {
#pragma unroll
            for (int j = 0; j < 4; ++j)
#pragma unroll
                for (int r = 0; r < 4; ++r)
                    sG[wm * 16 + quad * 4 + r][wn * 64 + j * 16 + lc] = acc[i][j][r];
            __syncthreads();
            int rl = tid >> 3;            // 0..31 chunk-local row
            int ub = (tid & 7) * 4;       // unit base 0..28
            int grow = tm * 128 + (rl >> 4) * 64 + i * 16 + (rl & 15);
#pragma unroll
            for (int uu = 0; uu < 4; ++uu) {
                int ul = ub + uu;
                float4 g = *(const float4*)&sG[rl][ul * 4];
                int gu = tn * 32 + ul;
                size_t off = (size_t)grow * HID + gu;
                float cold = cin_f32 ? ((const float*)c_in)[off]
                                     : bf2f(((const u16*)c_in)[off]);
                float iv = fsig(g.x), fv = fsig(g.y), gv = ftanh(g.z), ov = fsig(g.w);
                float c2 = fv * cold + iv * gv;
                float h2 = ov * ftanh(c2);
                if (cout_f) cout_f[off] = c2;
                if (cout_b) cout_b[off] = f2bf(c2);
                h_out[off] = f2bf(h2);
                if (hf_out) hf_out[off] = h2;
            }
            __syncthreads();
        }
    } else {
#pragma unroll
        for (int i = 0; i < 4; ++i)
#pragma unroll
            for (int j = 0; j < 4; ++j)
#pragma unroll
                for (int r = 0; r < 4; ++r) {
                    int grow = tm * 128 + wm * 64 + i * 16 + quad * 4 + r;
                    int gcol = tn * 128 + wn * 64 + j * 16 + lc;
                    lin_out[(size_t)grow * FEAT + gcol] = f2bf(acc[i][j][r]);
                }
    }
}

// permuted weight convert: dst row j' = 4*unit+gate <- src row gate*HID+unit, bf16
__global__ void convert_weight(const float* __restrict__ src, u16* __restrict__ dst,
                               int kshift, int permute) {
    int idx = blockIdx.x * 256 + threadIdx.x;
    int row = idx >> kshift;
    int k = idx & ((1 << kshift) - 1);
    int srow = permute ? ((row & 3) * HID + (row >> 2)) : row;
    dst[idx] = f2bf(src[((size_t)srow << kshift) | k]);
}

__global__ void combine_bias(const float* __restrict__ bi, const float* __restrict__ bh,
                             float* __restrict__ dst) {
    int j = blockIdx.x * 256 + threadIdx.x;  // 4096
    int s = (j & 3) * HID + (j >> 2);
    dst[j] = bi[s] + bh[s];
}

__global__ void init_state(const float* __restrict__ h0, const float* __restrict__ c0,
                           u16* __restrict__ chainHb, float* __restrict__ cf32) {
    int idx = blockIdx.x * 256 + threadIdx.x;  // 2*BAT*HID
    int l = idx >> 17;
    int off = idx & (int)(SLOT - 1);
    chainHb[(size_t)l * 97 * SLOT + off] = f2bf(h0[idx]);   // h slot 0
    cf32[(size_t)(l * 2 + 0) * SLOT + off] = c0[idx];       // c parity-0 slot
}

__global__ void copy_next(const u16* __restrict__ predsb, float* __restrict__ out) {
    int idx = blockIdx.x * 256 + threadIdx.x;  // BAT*FEAT
    out[idx] = bf2f(predsb[(size_t)95 * BAT * FEAT + idx]);
}

__global__ void gather_out(const float* __restrict__ inMusic, const u16* __restrict__ predsb,
                           float* __restrict__ outM) {
    int idx = blockIdx.x * 256 + threadIdx.x;  // 96*128*128*8
    int n = idx & 7;
    int f = (idx >> 3) & 127;
    int b = (idx >> 10) & 127;
    int r = idx >> 17;
    float v = 0.0f;
    if (r < NPRED && n >= r) {
        v = inMusic[((size_t)r * BAT + b) * FEAT + f];
    } else {
        int k = r - n - 1;
        if (n < k) v = bf2f(predsb[((size_t)n * MB + (size_t)k * BAT + b) * FEAT + f]);
    }
    outM[idx] = v;
}

__global__ void zero_out(float* __restrict__ o, int nmax) {
    int idx = blockIdx.x * 256 + threadIdx.x;
    if (idx < nmax) o[idx] = 0.0f;
}

extern "C" void kernel_launch(void* const* d_in, const int* in_sizes, int n_in,
                              void* d_out, int out_size, void* d_ws, size_t ws_size,
                              hipStream_t stream) {
    (void)in_sizes; (void)n_in;
    const float* inMusic = (const float*)d_in[0];
    const float* h0   = (const float*)d_in[1];
    const float* c0   = (const float*)d_in[2];
    const float* Wih0 = (const float*)d_in[3];
    const float* Whh0 = (const float*)d_in[4];
    const float* bih0 = (const float*)d_in[5];
    const float* bhh0 = (const float*)d_in[6];
    const float* Wih1 = (const float*)d_in[7];
    const float* Whh1 = (const float*)d_in[8];
    const float* bih1 = (const float*)d_in[9];
    const float* bhh1 = (const float*)d_in[10];
    const float* Wlin = (const float*)d_in[11];
    const float* blin = (const float*)d_in[12];
    float* out = (float*)d_out;

    const size_t OUT_H = (size_t)NSAMP * BAT * FEAT * NPRED;  // 12582912
    const size_t OUT_C = OUT_H + 2 * SLOT;
    const size_t OUT_NEXT = OUT_C + 2 * SLOT;

    char* ws = (char*)d_ws;
    size_t off = 0;
    auto alloc = [&](size_t bytes) {
        void* p = ws + off;
        off = (off + bytes + 255) & ~(size_t)255;
        return p;
    };
    u16* Wih0p = (u16*)alloc((size_t)GD * FEAT * 2);
    u16* Whh0p = (u16*)alloc((size_t)GD * HID * 2);
    u16* Wih1p = (u16*)alloc((size_t)GD * HID * 2);
    u16* Whh1p = (u16*)alloc((size_t)GD * HID * 2);
    u16* Wlinb = (u16*)alloc((size_t)FEAT * HID * 2);
    float* bp0 = (float*)alloc(GD * 4);
    float* bp1 = (float*)alloc(GD * 4);
    u16* chainHb = (u16*)alloc((size_t)2 * 97 * SLOT * 2);   // h slots 0..96, 2 layers
    u16* chainCb = (u16*)alloc((size_t)2 * 97 * SLOT * 2);   // bf16 c snapshots
    float* cf32  = (float*)alloc((size_t)2 * 2 * SLOT * 4);  // fp32 c ping-pong (filter)
    u16* hp2 = (u16*)alloc((size_t)2 * MB * HID * 2);        // phase-B h ping-pong
    u16* predsb = (u16*)alloc((size_t)NPRED * MB * FEAT * 2);

    if (off > ws_size) {
        // workspace too small: produce deterministic zeros (clean fail, no fault)
        zero_out<<<(out_size + 255) / 256, 256, 0, stream>>>(out, out_size);
        return;
    }

    convert_weight<<<(GD * FEAT) / 256, 256, 0, stream>>>(Wih0, Wih0p, 7, 1);
    convert_weight<<<(GD * HID) / 256, 256, 0, stream>>>(Whh0, Whh0p, 10, 1);
    convert_weight<<<(GD * HID) / 256, 256, 0, stream>>>(Wih1, Wih1p, 10, 1);
    convert_weight<<<(GD * HID) / 256, 256, 0, stream>>>(Whh1, Whh1p, 10, 1);
    convert_weight<<<(FEAT * HID) / 256, 256, 0, stream>>>(Wlin, Wlinb, 10, 0);
    combine_bias<<<GD / 256, 256, 0, stream>>>(bih0, bhh0, bp0);
    combine_bias<<<GD / 256, 256, 0, stream>>>(bih1, bhh1, bp1);
    init_state<<<(2 * (int)SLOT) / 256, 256, 0, stream>>>(h0, c0, chainHb, cf32);

    auto Hslot = [&](int l, int s) { return chainHb + ((size_t)l * 97 + s) * SLOT; };
    auto Cslot = [&](int l, int s) { return chainCb + ((size_t)l * 97 + s) * SLOT; };
    auto Cf = [&](int l, int p) { return cf32 + ((size_t)l * 2 + p) * SLOT; };

    dim3 blk(256);
    // ---- Phase A: sequential filter. step k reads h slot rk / c parity p_in,
    //      writes h slot k+1, c parity (k+1)&1, + bf16 c snapshot slot k+1.
    for (int k = 0; k < NSAMP; ++k) {
        int rk = (k <= 1) ? 0 : k;
        int pin = (k <= 1) ? 0 : (k & 1);
        int pout = (k + 1) & 1;
        gemm_lstm<<<dim3(32, 1), blk, 0, stream>>>(
            inMusic + (size_t)k * BAT * FEAT, 1, FEAT, Wih0p, FEAT,
            Hslot(0, rk), HID, Whh0p, HID, bp0,
            Cf(0, pin), 1,
            (k == 95) ? (out + OUT_C) : Cf(0, pout), Cslot(0, k + 1),
            Hslot(0, k + 1), (k == 95) ? (out + OUT_H) : nullptr,
            nullptr, 0);
        gemm_lstm<<<dim3(32, 1), blk, 0, stream>>>(
            Hslot(0, k + 1), 0, HID, Wih1p, HID,
            Hslot(1, rk), HID, Whh1p, HID, bp1,
            Cf(1, pin), 1,
            (k == 95) ? (out + OUT_C + SLOT) : Cf(1, pout), Cslot(1, k + 1),
            Hslot(1, k + 1), (k == 95) ? (out + OUT_H + SLOT) : nullptr,
            nullptr, 0);
    }

    // ---- Phase B: 96 chains batched (M = 12288). h ping-pong, bf16 c in place.
    u16* hbuf0[2] = {Hslot(0, 1), Hslot(1, 1)};
    u16* hbuf1[2] = {hp2, hp2 + (size_t)MB * HID};
    u16* cB[2] = {Cslot(0, 1), Cslot(1, 1)};

    gemm_lstm<<<dim3(1, 96), blk, 0, stream>>>(
        hbuf0[1], 0, HID, Wlinb, HID,
        nullptr, 0, nullptr, 0, blin,
        nullptr, 0, nullptr, nullptr, nullptr, nullptr,
        predsb, 1);
    copy_next<<<(BAT * FEAT) / 256, 256, 0, stream>>>(predsb, out + OUT_NEXT);

    for (int n = 1; n < NPRED; ++n) {
        u16* cur0 = (n & 1) ? hbuf0[0] : hbuf1[0];
        u16* cur1 = (n & 1) ? hbuf0[1] : hbuf1[1];
        u16* nxt0 = (n & 1) ? hbuf1[0] : hbuf0[0];
        u16* nxt1 = (n & 1) ? hbuf1[1] : hbuf0[1];
        const u16* pin = predsb + (size_t)(n - 1) * MB * FEAT;
        u16* pout = predsb + (size_t)n * MB * FEAT;
        gemm_lstm<<<dim3(32, 96), blk, 0, stream>>>(
            pin, 0, FEAT, Wih0p, FEAT,
            cur0, HID, Whh0p, HID, bp0,
            cB[0], 0, nullptr, cB[0],
            nxt0, nullptr, nullptr, 0);
        gemm_lstm<<<dim3(32, 96), blk, 0, stream>>>(
            nxt0, 0, HID, Wih1p, HID,
            cur1, HID, Whh1p, HID, bp1,
            cB[1], 0, nullptr, cB[1],
            nxt1, nullptr, nullptr, 0);
        gemm_lstm<<<dim3(1, 96), blk, 0, stream>>>(
            nxt1, 0, HID, Wlinb, HID,
            nullptr, 0, nullptr, 0, blin,
            nullptr, 0, nullptr, nullptr, nullptr, nullptr,
            pout, 1);
    }

    gather_out<<<(NSAMP * BAT * FEAT * NPRED) / 256, 256, 0, stream>>>(inMusic, predsb, out);
}

// Round 3
// 76813.226 us; speedup vs baseline: 1.1990x; 1.1990x over previous
//
#include <hip/hip_runtime.h>

#define HID 1024
#define FEAT 128
#define BAT 128
#define NSAMP 96
#define NPRED 8
#define GD 4096            // 4*HID
#define MB (NSAMP * BAT)   // 12288
#define SLOT ((size_t)BAT * HID)  // 131072

typedef unsigned short u16;
typedef short bf16x8 __attribute__((ext_vector_type(8)));
typedef float f32x4 __attribute__((ext_vector_type(4)));

__device__ inline u16 f2bf(float f) {
    unsigned u = __float_as_uint(f);
    u += 0x7FFFu + ((u >> 16) & 1u);
    return (u16)(u >> 16);
}
__device__ inline float bf2f(u16 h) { return __uint_as_float(((unsigned)h) << 16); }
__device__ inline float fsig(float x) { return 1.0f / (1.0f + __expf(-x)); }
__device__ inline float ftanh(float x) { return 1.0f - 2.0f / (__expf(2.0f * x) + 1.0f); }

#define LDSS 40  // panel row stride in shorts (32 + 8 pad)

// C[M,N] = A1[M,K1]*B1[N,K1]^T + A2[M,K2]*B2[N,K2]^T + bias, tile 128x128.
// K staged 64 at a time into two 32-wide LDS panels; register-prefetch dbuf.
// mode 0: LSTM epilogue (gate-interleaved cols: col = 4*unit + gate{i,f,g,o})
// mode 1: plain -> lin_out[M][128] (bf16)
// swz 1: XCD-aware remap (requires grid 32 x 96): tn-slice pinned per XCD.
__global__ __launch_bounds__(256, 2) void gemm_lstm(
    const void* A1, int a1f32, int lda1, const u16* __restrict__ B1, int K1,
    const u16* A2, int lda2, const u16* __restrict__ B2, int K2,
    const float* __restrict__ bias,
    const void* c_in, int cin_f32,
    float* cout_f, u16* cout_b,
    u16* h_out, float* hf_out,
    u16* lin_out, int mode, int swz)
{
    union SMem {
        struct { u16 a[2][128 * LDSS]; u16 b[2][128 * LDSS]; } st;
        float g[32][132];
    };
    __shared__ SMem sm;

    const int tid = threadIdx.x;
    int tn, tm;
    if (swz) {
        int L = blockIdx.y * gridDim.x + blockIdx.x;   // HW linear dispatch id
        int xcd = L & 7, slot = L >> 3;                // xcd round-robin
        tn = (xcd << 2) | (slot & 3);                  // 4 tn per XCD (B-slice resident)
        tm = slot >> 2;                                // tm-major per XCD (A reuse)
    } else { tn = blockIdx.x; tm = blockIdx.y; }
    const int wave = tid >> 6, lane = tid & 63;
    const int wm = wave >> 1, wn = wave & 1;
    const int quad = lane >> 4, lc = lane & 15;

    f32x4 acc[4][4];
#pragma unroll
    for (int j = 0; j < 4; ++j) {
        float bv = bias[tn * 128 + wn * 64 + j * 16 + lc];
        f32x4 bvv = {bv, bv, bv, bv};
#pragma unroll
        for (int i = 0; i < 4; ++i) acc[i][j] = bvv;
    }

    auto mfma_panels = [&]() {
#pragma unroll
        for (int p = 0; p < 2; ++p) {
            bf16x8 aF[4], bF[4];
#pragma unroll
            for (int i = 0; i < 4; ++i)
                aF[i] = *(const bf16x8*)&sm.st.a[p][(wm * 64 + i * 16 + lc) * LDSS + quad * 8];
#pragma unroll
            for (int j = 0; j < 4; ++j)
                bF[j] = *(const bf16x8*)&sm.st.b[p][(wn * 64 + j * 16 + lc) * LDSS + quad * 8];
#pragma unroll
            for (int i = 0; i < 4; ++i)
#pragma unroll
                for (int j = 0; j < 4; ++j)
                    acc[i][j] = __builtin_amdgcn_mfma_f32_16x16x32_bf16(aF[i], bF[j], acc[i][j], 0, 0, 0);
        }
    };

    for (int seg = 0; seg < 2; ++seg) {
        const int K = seg ? K2 : K1;
        if (K == 0) continue;
        const int lda = seg ? lda2 : lda1;
        const u16* Bb = (seg ? B2 : B1) + (size_t)tn * 128 * K;
        const int NIT = K >> 6;
        const int af32 = seg ? 0 : a1f32;
        const int br = tid >> 2, bc = (tid & 3) * 8;

        if (af32) {
            const float* Af = (const float*)A1 + (size_t)tm * 128 * lda;
            const int ar = tid >> 4, ac = (tid & 15) * 4;
            const int apan = ac >> 5, alc = ac & 31;
            float4 aR[8]; uint4 bR[2][2];
#pragma unroll
            for (int it = 0; it < 8; ++it)
                aR[it] = *(const float4*)(Af + (size_t)(it * 16 + ar) * lda + ac);
#pragma unroll
            for (int it = 0; it < 2; ++it)
#pragma unroll
                for (int h = 0; h < 2; ++h)
                    bR[it][h] = *(const uint4*)(Bb + (size_t)(it * 64 + br) * K + bc + h * 32);
            for (int ii = 0; ii < NIT; ++ii) {
                __syncthreads();
#pragma unroll
                for (int it = 0; it < 8; ++it) {
                    ushort4 pk = make_ushort4(f2bf(aR[it].x), f2bf(aR[it].y),
                                              f2bf(aR[it].z), f2bf(aR[it].w));
                    *(ushort4*)&sm.st.a[apan][(it * 16 + ar) * LDSS + alc] = pk;
                }
#pragma unroll
                for (int it = 0; it < 2; ++it)
#pragma unroll
                    for (int h = 0; h < 2; ++h)
                        *(uint4*)&sm.st.b[h][(it * 64 + br) * LDSS + bc] = bR[it][h];
                if (ii + 1 < NIT) {
                    int k0 = (ii + 1) * 64;
#pragma unroll
                    for (int it = 0; it < 8; ++it)
                        aR[it] = *(const float4*)(Af + (size_t)(it * 16 + ar) * lda + ac + k0);
#pragma unroll
                    for (int it = 0; it < 2; ++it)
#pragma unroll
                        for (int h = 0; h < 2; ++h)
                            bR[it][h] = *(const uint4*)(Bb + (size_t)(it * 64 + br) * K + k0 + bc + h * 32);
                }
                __syncthreads();
                mfma_panels();
            }
        } else {
            const u16* Ab = (const u16*)(seg ? (const void*)A2 : A1) + (size_t)tm * 128 * lda;
            uint4 aR[2][2], bR[2][2];
#pragma unroll
            for (int it = 0; it < 2; ++it)
#pragma unroll
                for (int h = 0; h < 2; ++h) {
                    aR[it][h] = *(const uint4*)(Ab + (size_t)(it * 64 + br) * lda + bc + h * 32);
                    bR[it][h] = *(const uint4*)(Bb + (size_t)(it * 64 + br) * K + bc + h * 32);
                }
            for (int ii = 0; ii < NIT; ++ii) {
                __syncthreads();
#pragma unroll
                for (int it = 0; it < 2; ++it)
#pragma unroll
                    for (int h = 0; h < 2; ++h) {
                        *(uint4*)&sm.st.a[h][(it * 64 + br) * LDSS + bc] = aR[it][h];
                        *(uint4*)&sm.st.b[h][(it * 64 + br) * LDSS + bc] = bR[it][h];
                    }
                if (ii + 1 < NIT) {
                    int k0 = (ii + 1) * 64;
#pragma unroll
                    for (int it = 0; it < 2; ++it)
#pragma unroll
                        for (int h = 0; h < 2; ++h) {
                            aR[it][h] = *(const uint4*)(Ab + (size_t)(it * 64 + br) * lda + k0 + bc + h * 32);
                            bR[it][h] = *(const uint4*)(Bb + (size_t)(it * 64 + br) * K + k0 + bc + h * 32);
                        }
                }
                __syncthreads();
                mfma_panels();
            }
        }
    }

    if (mode == 0) {
        __syncthreads();   // sG aliases sA/sB: ensure all waves' frag reads are done
#pragma unroll 1
        for (int i = 0; i < 4; ++i) {
#pragma unroll
            for (int j = 0; j < 4; ++j)
#pragma unroll
                for (int r = 0; r < 4; ++r)
                    sm.g[wm * 16 + quad * 4 + r][wn * 64 + j * 16 + lc] = acc[i][j][r];
            __syncthreads();
            int rl = tid >> 3;            // 0..31 chunk-local row
            int ub = (tid & 7) * 4;       // unit base 0..28
            int grow = tm * 128 + (rl >> 4) * 64 + i * 16 + (rl & 15);
#pragma unroll
            for (int uu = 0; uu < 4; ++uu) {
                int ul = ub + uu;
                float4 g = *(const float4*)&sm.g[rl][ul * 4];
                int gu = tn * 32 + ul;
                size_t off = (size_t)grow * HID + gu;
                float cold = cin_f32 ? ((const float*)c_in)[off]
                                     : bf2f(((const u16*)c_in)[off]);
                float iv = fsig(g.x), fv = fsig(g.y), gv = ftanh(g.z), ov = fsig(g.w);
                float c2 = fv * cold + iv * gv;
                float h2 = ov * ftanh(c2);
                if (cout_f) cout_f[off] = c2;
                if (cout_b) cout_b[off] = f2bf(c2);
                h_out[off] = f2bf(h2);
                if (hf_out) hf_out[off] = h2;
            }
            __syncthreads();
        }
    } else {
#pragma unroll
        for (int i = 0; i < 4; ++i)
#pragma unroll
            for (int j = 0; j < 4; ++j)
#pragma unroll
                for (int r = 0; r < 4; ++r) {
                    int grow = tm * 128 + wm * 64 + i * 16 + quad * 4 + r;
                    int gcol = tn * 128 + wn * 64 + j * 16 + lc;
                    lin_out[(size_t)grow * FEAT + gcol] = f2bf(acc[i][j][r]);
                }
    }
}

// permuted weight convert: dst row j' = 4*unit+gate <- src row gate*HID+unit, bf16
__global__ void convert_weight(const float* __restrict__ src, u16* __restrict__ dst,
                               int kshift, int permute) {
    int idx = blockIdx.x * 256 + threadIdx.x;
    int row = idx >> kshift;
    int k = idx & ((1 << kshift) - 1);
    int srow = permute ? ((row & 3) * HID + (row >> 2)) : row;
    dst[idx] = f2bf(src[((size_t)srow << kshift) | k]);
}

__global__ void combine_bias(const float* __restrict__ bi, const float* __restrict__ bh,
                             float* __restrict__ dst) {
    int j = blockIdx.x * 256 + threadIdx.x;  // 4096
    int s = (j & 3) * HID + (j >> 2);
    dst[j] = bi[s] + bh[s];
}

__global__ void init_state(const float* __restrict__ h0, const float* __restrict__ c0,
                           u16* __restrict__ chainHb, float* __restrict__ cf32) {
    int idx = blockIdx.x * 256 + threadIdx.x;  // 2*BAT*HID
    int l = idx >> 17;
    int off = idx & (int)(SLOT - 1);
    chainHb[(size_t)l * 97 * SLOT + off] = f2bf(h0[idx]);   // h slot 0
    cf32[(size_t)(l * 2 + 0) * SLOT + off] = c0[idx];       // c parity-0 slot
}

__global__ void copy_next(const u16* __restrict__ predsb, float* __restrict__ out) {
    int idx = blockIdx.x * 256 + threadIdx.x;  // BAT*FEAT
    out[idx] = bf2f(predsb[(size_t)95 * BAT * FEAT + idx]);
}

__global__ void gather_out(const float* __restrict__ inMusic, const u16* __restrict__ predsb,
                           float* __restrict__ outM) {
    int idx = blockIdx.x * 256 + threadIdx.x;  // 96*128*128*8
    int n = idx & 7;
    int f = (idx >> 3) & 127;
    int b = (idx >> 10) & 127;
    int r = idx >> 17;
    float v = 0.0f;
    if (r < NPRED && n >= r) {
        v = inMusic[((size_t)r * BAT + b) * FEAT + f];
    } else {
        int k = r - n - 1;
        if (n < k) v = bf2f(predsb[((size_t)n * MB + (size_t)k * BAT + b) * FEAT + f]);
    }
    outM[idx] = v;
}

__global__ void zero_out(float* __restrict__ o, int nmax) {
    int idx = blockIdx.x * 256 + threadIdx.x;
    if (idx < nmax) o[idx] = 0.0f;
}

extern "C" void kernel_launch(void* const* d_in, const int* in_sizes, int n_in,
                              void* d_out, int out_size, void* d_ws, size_t ws_size,
                              hipStream_t stream) {
    (void)in_sizes; (void)n_in;
    const float* inMusic = (const float*)d_in[0];
    const float* h0   = (const float*)d_in[1];
    const float* c0   = (const float*)d_in[2];
    const float* Wih0 = (const float*)d_in[3];
    const float* Whh0 = (const float*)d_in[4];
    const float* bih0 = (const float*)d_in[5];
    const float* bhh0 = (const float*)d_in[6];
    const float* Wih1 = (const float*)d_in[7];
    const float* Whh1 = (const float*)d_in[8];
    const float* bih1 = (const float*)d_in[9];
    const float* bhh1 = (const float*)d_in[10];
    const float* Wlin = (const float*)d_in[11];
    const float* blin = (const float*)d_in[12];
    float* out = (float*)d_out;

    const size_t OUT_H = (size_t)NSAMP * BAT * FEAT * NPRED;  // 12582912
    const size_t OUT_C = OUT_H + 2 * SLOT;
    const size_t OUT_NEXT = OUT_C + 2 * SLOT;

    char* ws = (char*)d_ws;
    size_t off = 0;
    auto alloc = [&](size_t bytes) {
        void* p = ws + off;
        off = (off + bytes + 255) & ~(size_t)255;
        return p;
    };
    u16* Wih0p = (u16*)alloc((size_t)GD * FEAT * 2);
    u16* Whh0p = (u16*)alloc((size_t)GD * HID * 2);
    u16* Wih1p = (u16*)alloc((size_t)GD * HID * 2);
    u16* Whh1p = (u16*)alloc((size_t)GD * HID * 2);
    u16* Wlinb = (u16*)alloc((size_t)FEAT * HID * 2);
    float* bp0 = (float*)alloc(GD * 4);
    float* bp1 = (float*)alloc(GD * 4);
    u16* chainHb = (u16*)alloc((size_t)2 * 97 * SLOT * 2);   // h slots 0..96, 2 layers
    u16* chainCb = (u16*)alloc((size_t)2 * 97 * SLOT * 2);   // bf16 c snapshots
    float* cf32  = (float*)alloc((size_t)2 * 2 * SLOT * 4);  // fp32 c ping-pong (filter)
    u16* hp2 = (u16*)alloc((size_t)2 * MB * HID * 2);        // phase-B h ping-pong
    u16* predsb = (u16*)alloc((size_t)NPRED * MB * FEAT * 2);

    if (off > ws_size) {
        zero_out<<<(out_size + 255) / 256, 256, 0, stream>>>(out, out_size);
        return;
    }

    convert_weight<<<(GD * FEAT) / 256, 256, 0, stream>>>(Wih0, Wih0p, 7, 1);
    convert_weight<<<(GD * HID) / 256, 256, 0, stream>>>(Whh0, Whh0p, 10, 1);
    convert_weight<<<(GD * HID) / 256, 256, 0, stream>>>(Wih1, Wih1p, 10, 1);
    convert_weight<<<(GD * HID) / 256, 256, 0, stream>>>(Whh1, Whh1p, 10, 1);
    convert_weight<<<(FEAT * HID) / 256, 256, 0, stream>>>(Wlin, Wlinb, 10, 0);
    combine_bias<<<GD / 256, 256, 0, stream>>>(bih0, bhh0, bp0);
    combine_bias<<<GD / 256, 256, 0, stream>>>(bih1, bhh1, bp1);
    init_state<<<(2 * (int)SLOT) / 256, 256, 0, stream>>>(h0, c0, chainHb, cf32);

    auto Hslot = [&](int l, int s) { return chainHb + ((size_t)l * 97 + s) * SLOT; };
    auto Cslot = [&](int l, int s) { return chainCb + ((size_t)l * 97 + s) * SLOT; };
    auto Cf = [&](int l, int p) { return cf32 + ((size_t)l * 2 + p) * SLOT; };

    dim3 blk(256);
    // ---- Phase A: sequential filter. step k reads h slot rk / c parity p_in,
    //      writes h slot k+1, c parity (k+1)&1, + bf16 c snapshot slot k+1.
    for (int k = 0; k < NSAMP; ++k) {
        int rk = (k <= 1) ? 0 : k;
        int pin = (k <= 1) ? 0 : (k & 1);
        int pout = (k + 1) & 1;
        gemm_lstm<<<dim3(32, 1), blk, 0, stream>>>(
            inMusic + (size_t)k * BAT * FEAT, 1, FEAT, Wih0p, FEAT,
            Hslot(0, rk), HID, Whh0p, HID, bp0,
            Cf(0, pin), 1,
            (k == 95) ? (out + OUT_C) : Cf(0, pout), Cslot(0, k + 1),
            Hslot(0, k + 1), (k == 95) ? (out + OUT_H) : nullptr,
            nullptr, 0, 0);
        gemm_lstm<<<dim3(32, 1), blk, 0, stream>>>(
            Hslot(0, k + 1), 0, HID, Wih1p, HID,
            Hslot(1, rk), HID, Whh1p, HID, bp1,
            Cf(1, pin), 1,
            (k == 95) ? (out + OUT_C + SLOT) : Cf(1, pout), Cslot(1, k + 1),
            Hslot(1, k + 1), (k == 95) ? (out + OUT_H + SLOT) : nullptr,
            nullptr, 0, 0);
    }

    // ---- Phase B: 96 chains batched (M = 12288). h ping-pong, bf16 c in place.
    u16* hbuf0[2] = {Hslot(0, 1), Hslot(1, 1)};
    u16* hbuf1[2] = {hp2, hp2 + (size_t)MB * HID};
    u16* cB[2] = {Cslot(0, 1), Cslot(1, 1)};

    gemm_lstm<<<dim3(1, 96), blk, 0, stream>>>(
        hbuf0[1], 0, HID, Wlinb, HID,
        nullptr, 0, nullptr, 0, blin,
        nullptr, 0, nullptr, nullptr, nullptr, nullptr,
        predsb, 1, 0);
    copy_next<<<(BAT * FEAT) / 256, 256, 0, stream>>>(predsb, out + OUT_NEXT);

    for (int n = 1; n < NPRED; ++n) {
        u16* cur0 = (n & 1) ? hbuf0[0] : hbuf1[0];
        u16* cur1 = (n & 1) ? hbuf0[1] : hbuf1[1];
        u16* nxt0 = (n & 1) ? hbuf1[0] : hbuf0[0];
        u16* nxt1 = (n & 1) ? hbuf1[1] : hbuf0[1];
        const u16* pin = predsb + (size_t)(n - 1) * MB * FEAT;
        u16* pout = predsb + (size_t)n * MB * FEAT;
        gemm_lstm<<<dim3(32, 96), blk, 0, stream>>>(
            pin, 0, FEAT, Wih0p, FEAT,
            cur0, HID, Whh0p, HID, bp0,
            cB[0], 0, nullptr, cB[0],
            nxt0, nullptr, nullptr, 0, 1);
        gemm_lstm<<<dim3(32, 96), blk, 0, stream>>>(
            nxt0, 0, HID, Wih1p, HID,
            cur1, HID, Whh1p, HID, bp1,
            cB[1], 0, nullptr, cB[1],
            nxt1, nullptr, nullptr, 0, 1);
        gemm_lstm<<<dim3(1, 96), blk, 0, stream>>>(
            nxt1, 0, HID, Wlinb, HID,
            nullptr, 0, nullptr, 0, blin,
            nullptr, 0, nullptr, nullptr, nullptr, nullptr,
            pout, 1, 0);
    }

    gather_out<<<(NSAMP * BAT * FEAT * NPRED) / 256, 256, 0, stream>>>(inMusic, predsb, out);
}

// Round 4
// 64435.284 us; speedup vs baseline: 1.4294x; 1.1921x over previous
//
#include <hip/hip_runtime.h>

#define HID 1024
#define FEAT 128
#define BAT 128
#define NSAMP 96
#define NPRED 8
#define GD 4096                    // 4*HID
#define MB (NSAMP * BAT)           // 12288
#define SLOTE ((size_t)BAT * HID)  // 131072 elements per 128-row state slot

typedef unsigned short u16;
typedef short bf16x8 __attribute__((ext_vector_type(8)));
typedef float f32x4 __attribute__((ext_vector_type(4)));

__device__ inline u16 f2bf(float f) {
    unsigned u = __float_as_uint(f);
    u += 0x7FFFu + ((u >> 16) & 1u);
    return (u16)(u >> 16);
}
__device__ inline float bf2f(u16 h) { return __uint_as_float(((unsigned)h) << 16); }
__device__ inline float fsig(float x) { return 1.0f / (1.0f + __expf(-x)); }
__device__ inline float ftanh(float x) { return 1.0f - 2.0f / (__expf(2.0f * x) + 1.0f); }

#define LDSS 40  // LDS panel row stride in shorts (32 + 8 pad)

// ---- State layout: "slot-panel". A 128-row state slot ([128][1024] logically)
// is stored as [32 panels][128 rows][32 units]; panel p holds units p*32..p*32+31.
// Block (tn,tm) owns panel tn of slot tm exclusively -> contiguous full-line
// writes, no cross-block/cross-XCD line sharing (fixes 260x write amplification).

struct GArgs {
    const void* A1; const void* A2;      // aL: 0 = f32 row-major, 1 = bf16 row-major, 2 = bf16 slot-panel
    const u16 *B1, *B2;                  // row-major [N][K], K-contiguous
    const float* bias;                   // gate-interleaved for mode 0
    const void* c_in;                    // slot-panel (f32 or bf16 per cin_f32)
    float* cout_f;                       // slot-panel f32 (or null)
    u16* cout_b;                         // slot-panel bf16 (or null)
    u16* h_out;                          // slot-panel bf16 (mode 0)
    float* c_std; float* h_std;          // standard [row][HID] f32 finals (or null)
    u16* lin_out;                        // mode 1 output, row-major [M][128] bf16
    int aL1, lda1, K1, aL2, lda2, K2;
    int cin_f32, mode, active;
};

// dual=1: grid(32,2), y=0 -> ga, y=1 -> gb, tm=0 (two independent GEMMs fused).
// dual=0: grid(32|1, 96), all blocks ga, tn=bx, tm=by.
__global__ __launch_bounds__(256, 2) void gemm_lstm(GArgs ga, GArgs gb, int dual)
{
    union SMem {
        struct { u16 a[2][128 * LDSS]; u16 b[2][128 * LDSS]; } st;
        float g[32][132];
    };
    __shared__ SMem sm;

    const int tid = threadIdx.x;
    int tn, tm;
    GArgs g;
    if (dual) { tn = blockIdx.x; tm = 0; g = blockIdx.y ? gb : ga; }
    else      { tn = blockIdx.x; tm = blockIdx.y; g = ga; }
    if (!g.active) return;

    const int wave = tid >> 6, lane = tid & 63;
    const int wm = wave >> 1, wn = wave & 1;
    const int quad = lane >> 4, lc = lane & 15;

    f32x4 acc[4][4];
#pragma unroll
    for (int j = 0; j < 4; ++j) {
        float bv = g.bias[tn * 128 + wn * 64 + j * 16 + lc];
        f32x4 bvv = {bv, bv, bv, bv};
#pragma unroll
        for (int i = 0; i < 4; ++i) acc[i][j] = bvv;
    }

    auto mfma_panels = [&]() {
#pragma unroll
        for (int p = 0; p < 2; ++p) {
            bf16x8 aF[4], bF[4];
#pragma unroll
            for (int i = 0; i < 4; ++i)
                aF[i] = *(const bf16x8*)&sm.st.a[p][(wm * 64 + i * 16 + lc) * LDSS + quad * 8];
#pragma unroll
            for (int j = 0; j < 4; ++j)
                bF[j] = *(const bf16x8*)&sm.st.b[p][(wn * 64 + j * 16 + lc) * LDSS + quad * 8];
#pragma unroll
            for (int i = 0; i < 4; ++i)
#pragma unroll
                for (int j = 0; j < 4; ++j)
                    acc[i][j] = __builtin_amdgcn_mfma_f32_16x16x32_bf16(aF[i], bF[j], acc[i][j], 0, 0, 0);
        }
    };

    for (int seg = 0; seg < 2; ++seg) {
        const int K = seg ? g.K2 : g.K1;
        if (K == 0) continue;
        const int aL = seg ? g.aL2 : g.aL1;
        const int lda = seg ? g.lda2 : g.lda1;
        const void* Ap = seg ? g.A2 : g.A1;
        const u16* Bb = (seg ? g.B2 : g.B1) + (size_t)tn * 128 * K;
        const int NIT = K >> 6;
        const int br = tid >> 2, bc = (tid & 3) * 8;

        if (aL == 0) {
            const float* Af = (const float*)Ap + (size_t)tm * 128 * lda;
            const int ar = tid >> 4, ac = (tid & 15) * 4;
            const int apan = ac >> 5, alc = ac & 31;
            float4 aR[8]; uint4 bR[2][2];
#pragma unroll
            for (int it = 0; it < 8; ++it)
                aR[it] = *(const float4*)(Af + (size_t)(it * 16 + ar) * lda + ac);
#pragma unroll
            for (int it = 0; it < 2; ++it)
#pragma unroll
                for (int h = 0; h < 2; ++h)
                    bR[it][h] = *(const uint4*)(Bb + (size_t)(it * 64 + br) * K + bc + h * 32);
            for (int ii = 0; ii < NIT; ++ii) {
                __syncthreads();
#pragma unroll
                for (int it = 0; it < 8; ++it) {
                    ushort4 pk = make_ushort4(f2bf(aR[it].x), f2bf(aR[it].y),
                                              f2bf(aR[it].z), f2bf(aR[it].w));
                    *(ushort4*)&sm.st.a[apan][(it * 16 + ar) * LDSS + alc] = pk;
                }
#pragma unroll
                for (int it = 0; it < 2; ++it)
#pragma unroll
                    for (int h = 0; h < 2; ++h)
                        *(uint4*)&sm.st.b[h][(it * 64 + br) * LDSS + bc] = bR[it][h];
                if (ii + 1 < NIT) {
                    int k0 = (ii + 1) * 64;
#pragma unroll
                    for (int it = 0; it < 8; ++it)
                        aR[it] = *(const float4*)(Af + (size_t)(it * 16 + ar) * lda + ac + k0);
#pragma unroll
                    for (int it = 0; it < 2; ++it)
#pragma unroll
                        for (int h = 0; h < 2; ++h)
                            bR[it][h] = *(const uint4*)(Bb + (size_t)(it * 64 + br) * K + k0 + bc + h * 32);
                }
                __syncthreads();
                mfma_panels();
            }
        } else {
            // bf16 sources: row-major (aL==1) or slot-panel (aL==2)
            const u16* Ab = (const u16*)Ap +
                (aL == 2 ? (size_t)tm * SLOTE : (size_t)tm * 128 * lda);
            auto aoff = [&](int row, int k0, int h) -> size_t {
                if (aL == 1) return (size_t)row * lda + k0 + h * 32 + bc;
                return ((size_t)((k0 >> 5) + h) * 128 + row) * 32 + bc;
            };
            uint4 aR[2][2], bR[2][2];
#pragma unroll
            for (int it = 0; it < 2; ++it)
#pragma unroll
                for (int h = 0; h < 2; ++h) {
                    aR[it][h] = *(const uint4*)(Ab + aoff(it * 64 + br, 0, h));
                    bR[it][h] = *(const uint4*)(Bb + (size_t)(it * 64 + br) * K + bc + h * 32);
                }
            for (int ii = 0; ii < NIT; ++ii) {
                __syncthreads();
#pragma unroll
                for (int it = 0; it < 2; ++it)
#pragma unroll
                    for (int h = 0; h < 2; ++h) {
                        *(uint4*)&sm.st.a[h][(it * 64 + br) * LDSS + bc] = aR[it][h];
                        *(uint4*)&sm.st.b[h][(it * 64 + br) * LDSS + bc] = bR[it][h];
                    }
                if (ii + 1 < NIT) {
                    int k0 = (ii + 1) * 64;
#pragma unroll
                    for (int it = 0; it < 2; ++it)
#pragma unroll
                        for (int h = 0; h < 2; ++h) {
                            aR[it][h] = *(const uint4*)(Ab + aoff(it * 64 + br, k0, h));
                            bR[it][h] = *(const uint4*)(Bb + (size_t)(it * 64 + br) * K + k0 + bc + h * 32);
                        }
                }
                __syncthreads();
                mfma_panels();
            }
        }
    }

    if (g.mode == 0) {
        __syncthreads();   // sG aliases sA/sB
#pragma unroll 1
        for (int i = 0; i < 4; ++i) {
#pragma unroll
            for (int j = 0; j < 4; ++j)
#pragma unroll
                for (int r = 0; r < 4; ++r)
                    sm.g[wm * 16 + quad * 4 + r][wn * 64 + j * 16 + lc] = acc[i][j][r];
            __syncthreads();
            int rl = tid >> 3;            // 0..31 chunk-local row
            int ub = (tid & 7) * 4;       // unit base 0..28 (4 consecutive units)
            int lrow = (rl >> 4) * 64 + i * 16 + (rl & 15);   // local row 0..127
            size_t pOff = (size_t)tm * SLOTE + ((size_t)tn * 128 + lrow) * 32 + ub;
            float cold[4];
            if (g.cin_f32) {
                float4 c4 = *(const float4*)((const float*)g.c_in + pOff);
                cold[0] = c4.x; cold[1] = c4.y; cold[2] = c4.z; cold[3] = c4.w;
            } else {
                ushort4 c4 = *(const ushort4*)((const u16*)g.c_in + pOff);
                cold[0] = bf2f(c4.x); cold[1] = bf2f(c4.y);
                cold[2] = bf2f(c4.z); cold[3] = bf2f(c4.w);
            }
            float c2v[4], h2v[4];
#pragma unroll
            for (int uu = 0; uu < 4; ++uu) {
                float4 gg = *(const float4*)&sm.g[rl][(ub + uu) * 4];
                float iv = fsig(gg.x), fv = fsig(gg.y), gv = ftanh(gg.z), ov = fsig(gg.w);
                float c2 = fv * cold[uu] + iv * gv;
                c2v[uu] = c2;
                h2v[uu] = ov * ftanh(c2);
            }
            if (g.cout_f)
                *(float4*)(g.cout_f + pOff) = make_float4(c2v[0], c2v[1], c2v[2], c2v[3]);
            if (g.cout_b)
                *(ushort4*)(g.cout_b + pOff) =
                    make_ushort4(f2bf(c2v[0]), f2bf(c2v[1]), f2bf(c2v[2]), f2bf(c2v[3]));
            *(ushort4*)(g.h_out + pOff) =
                make_ushort4(f2bf(h2v[0]), f2bf(h2v[1]), f2bf(h2v[2]), f2bf(h2v[3]));
            if (g.h_std || g.c_std) {
                size_t sOff = (size_t)(tm * 128 + lrow) * HID + tn * 32 + ub;
                if (g.h_std)
                    *(float4*)(g.h_std + sOff) = make_float4(h2v[0], h2v[1], h2v[2], h2v[3]);
                if (g.c_std)
                    *(float4*)(g.c_std + sOff) = make_float4(c2v[0], c2v[1], c2v[2], c2v[3]);
            }
            __syncthreads();
        }
    } else {
#pragma unroll
        for (int i = 0; i < 4; ++i)
#pragma unroll
            for (int j = 0; j < 4; ++j)
#pragma unroll
                for (int r = 0; r < 4; ++r) {
                    int grow = tm * 128 + wm * 64 + i * 16 + quad * 4 + r;
                    int gcol = tn * 128 + wn * 64 + j * 16 + lc;
                    g.lin_out[(size_t)grow * FEAT + gcol] = f2bf(acc[i][j][r]);
                }
    }
}

// permuted weight convert: dst row j' = 4*unit+gate <- src row gate*HID+unit, bf16
__global__ void convert_weight(const float* __restrict__ src, u16* __restrict__ dst,
                               int kshift, int permute) {
    int idx = blockIdx.x * 256 + threadIdx.x;
    int row = idx >> kshift;
    int k = idx & ((1 << kshift) - 1);
    int srow = permute ? ((row & 3) * HID + (row >> 2)) : row;
    dst[idx] = f2bf(src[((size_t)srow << kshift) | k]);
}

__global__ void combine_bias(const float* __restrict__ bi, const float* __restrict__ bh,
                             float* __restrict__ dst) {
    int j = blockIdx.x * 256 + threadIdx.x;  // 4096
    int s = (j & 3) * HID + (j >> 2);
    dst[j] = bi[s] + bh[s];
}

// h0/c0 [l][b][h] -> slot-panel slot 0 (h chain) / parity 0 (c f32 ping-pong)
__global__ void init_state(const float* __restrict__ h0, const float* __restrict__ c0,
                           u16* __restrict__ chainHb, float* __restrict__ cf32) {
    int idx = blockIdx.x * 256 + threadIdx.x;  // 2*BAT*HID
    int l = idx >> 17;
    int r = idx & (int)(SLOTE - 1);
    int b = r >> 10, hh = r & 1023;
    size_t po = ((size_t)(hh >> 5) * 128 + b) * 32 + (hh & 31);
    chainHb[(size_t)l * 97 * SLOTE + po] = f2bf(h0[idx]);
    cf32[(size_t)l * 2 * SLOTE + po] = c0[idx];
}

__global__ void copy_next(const u16* __restrict__ predsb, float* __restrict__ out) {
    int idx = blockIdx.x * 256 + threadIdx.x;  // BAT*FEAT
    out[idx] = bf2f(predsb[(size_t)95 * BAT * FEAT + idx]);
}

__global__ void gather_out(const float* __restrict__ inMusic, const u16* __restrict__ predsb,
                           float* __restrict__ outM) {
    int idx = blockIdx.x * 256 + threadIdx.x;  // 96*128*128*8
    int n = idx & 7;
    int f = (idx >> 3) & 127;
    int b = (idx >> 10) & 127;
    int r = idx >> 17;
    float v = 0.0f;
    if (r < NPRED && n >= r) {
        v = inMusic[((size_t)r * BAT + b) * FEAT + f];
    } else {
        int k = r - n - 1;
        if (n < k) v = bf2f(predsb[((size_t)n * MB + (size_t)k * BAT + b) * FEAT + f]);
    }
    outM[idx] = v;
}

__global__ void zero_out(float* __restrict__ o, int nmax) {
    int idx = blockIdx.x * 256 + threadIdx.x;
    if (idx < nmax) o[idx] = 0.0f;
}

extern "C" void kernel_launch(void* const* d_in, const int* in_sizes, int n_in,
                              void* d_out, int out_size, void* d_ws, size_t ws_size,
                              hipStream_t stream) {
    (void)in_sizes; (void)n_in;
    const float* inMusic = (const float*)d_in[0];
    const float* h0   = (const float*)d_in[1];
    const float* c0   = (const float*)d_in[2];
    const float* Wih0 = (const float*)d_in[3];
    const float* Whh0 = (const float*)d_in[4];
    const float* bih0 = (const float*)d_in[5];
    const float* bhh0 = (const float*)d_in[6];
    const float* Wih1 = (const float*)d_in[7];
    const float* Whh1 = (const float*)d_in[8];
    const float* bih1 = (const float*)d_in[9];
    const float* bhh1 = (const float*)d_in[10];
    const float* Wlin = (const float*)d_in[11];
    const float* blin = (const float*)d_in[12];
    float* out = (float*)d_out;

    const size_t OUT_H = (size_t)NSAMP * BAT * FEAT * NPRED;  // 12582912
    const size_t OUT_C = OUT_H + 2 * SLOTE;
    const size_t OUT_NEXT = OUT_C + 2 * SLOTE;

    char* ws = (char*)d_ws;
    size_t off = 0;
    auto alloc = [&](size_t bytes) {
        void* p = ws + off;
        off = (off + bytes + 255) & ~(size_t)255;
        return p;
    };
    u16* Wih0p = (u16*)alloc((size_t)GD * FEAT * 2);
    u16* Whh0p = (u16*)alloc((size_t)GD * HID * 2);
    u16* Wih1p = (u16*)alloc((size_t)GD * HID * 2);
    u16* Whh1p = (u16*)alloc((size_t)GD * HID * 2);
    u16* Wlinb = (u16*)alloc((size_t)FEAT * HID * 2);
    float* bp0 = (float*)alloc(GD * 4);
    float* bp1 = (float*)alloc(GD * 4);
    u16* chainHb = (u16*)alloc((size_t)2 * 97 * SLOTE * 2);   // h slots 0..96 x2 layers (slot-panel)
    u16* chainCb = (u16*)alloc((size_t)2 * 97 * SLOTE * 2);   // bf16 c snapshots (slot-panel)
    float* cf32  = (float*)alloc((size_t)2 * 2 * SLOTE * 4);  // f32 c ping-pong (slot-panel)
    u16* hp2 = (u16*)alloc((size_t)2 * (size_t)NSAMP * SLOTE * 2);  // phase-B h ping-pong
    u16* predsb = (u16*)alloc((size_t)NPRED * MB * FEAT * 2);

    if (off > ws_size) {
        zero_out<<<((int)((OUT_NEXT + BAT * FEAT) + 255)) / 256 + 1, 256, 0, stream>>>(out, out_size);
        return;
    }

    convert_weight<<<(GD * FEAT) / 256, 256, 0, stream>>>(Wih0, Wih0p, 7, 1);
    convert_weight<<<(GD * HID) / 256, 256, 0, stream>>>(Whh0, Whh0p, 10, 1);
    convert_weight<<<(GD * HID) / 256, 256, 0, stream>>>(Wih1, Wih1p, 10, 1);
    convert_weight<<<(GD * HID) / 256, 256, 0, stream>>>(Whh1, Whh1p, 10, 1);
    convert_weight<<<(FEAT * HID) / 256, 256, 0, stream>>>(Wlin, Wlinb, 10, 0);
    combine_bias<<<GD / 256, 256, 0, stream>>>(bih0, bhh0, bp0);
    combine_bias<<<GD / 256, 256, 0, stream>>>(bih1, bhh1, bp1);
    init_state<<<(int)(2 * SLOTE) / 256, 256, 0, stream>>>(h0, c0, chainHb, cf32);

    auto Hs = [&](int l, int s) { return chainHb + ((size_t)l * 97 + s) * SLOTE; };
    auto Cs = [&](int l, int s) { return chainCb + ((size_t)l * 97 + s) * SLOTE; };
    auto Cf = [&](int l, int p) { return cf32 + ((size_t)l * 2 + p) * SLOTE; };

    GArgs gz = {};  // inactive placeholder

    auto mkA = [&](int l, int k) {  // phase-A step k, layer l
        GArgs a = {};
        int rk = (k <= 1) ? 0 : k;
        int pin = (k <= 1) ? 0 : (k & 1);
        int pout = (k + 1) & 1;
        if (l == 0) {
            a.A1 = inMusic + (size_t)k * BAT * FEAT; a.aL1 = 0; a.lda1 = FEAT; a.K1 = FEAT;
            a.B1 = Wih0p; a.B2 = Whh0p; a.bias = bp0;
        } else {
            a.A1 = Hs(0, k + 1); a.aL1 = 2; a.lda1 = 0; a.K1 = HID;
            a.B1 = Wih1p; a.B2 = Whh1p; a.bias = bp1;
        }
        a.A2 = Hs(l, rk); a.aL2 = 2; a.lda2 = 0; a.K2 = HID;
        a.c_in = Cf(l, pin); a.cin_f32 = 1;
        a.cout_f = Cf(l, pout);
        a.cout_b = Cs(l, k + 1);
        a.h_out = Hs(l, k + 1);
        a.c_std = (k == 95) ? (out + OUT_C + (size_t)l * SLOTE) : nullptr;
        a.h_std = (k == 95) ? (out + OUT_H + (size_t)l * SLOTE) : nullptr;
        a.mode = 0; a.active = 1;
        return a;
    };

    dim3 blk(256);
    // ---- Phase A: 97 paired dispatches; dispatch d runs L1(d-1) || L0(d).
    for (int d = 0; d <= NSAMP; ++d) {
        GArgs gA = (d >= 1) ? mkA(1, d - 1) : gz;
        GArgs gB = (d <= NSAMP - 1) ? mkA(0, d) : gz;
        gemm_lstm<<<dim3(32, 2), blk, 0, stream>>>(gA, gB, 1);
    }

    // ---- Phase B: 96 chains batched (M = 12288, 96 slots). h ping-pong, bf16 c in place.
    u16* hbuf0[2] = {Hs(0, 1), Hs(1, 1)};
    u16* hbuf1[2] = {hp2, hp2 + (size_t)NSAMP * SLOTE};
    u16* cB[2] = {Cs(0, 1), Cs(1, 1)};

    auto mkLin = [&](const u16* src, u16* dst) {
        GArgs a = {};
        a.A1 = src; a.aL1 = 2; a.lda1 = 0; a.K1 = HID;
        a.B1 = Wlinb; a.bias = blin;
        a.lin_out = dst; a.mode = 1; a.active = 1;
        return a;
    };
    auto mkB = [&](int l, const void* A1, int aL1, const u16* A2, u16* nxt) {
        GArgs a = {};
        a.A1 = A1; a.aL1 = aL1; a.lda1 = (aL1 == 1) ? FEAT : 0; a.K1 = (aL1 == 1) ? FEAT : HID;
        a.A2 = A2; a.aL2 = 2; a.lda2 = 0; a.K2 = HID;
        a.B1 = (l == 0) ? Wih0p : Wih1p; a.B2 = (l == 0) ? Whh0p : Whh1p;
        a.bias = (l == 0) ? bp0 : bp1;
        a.c_in = cB[l]; a.cin_f32 = 0; a.cout_b = cB[l];
        a.h_out = nxt; a.mode = 0; a.active = 1;
        return a;
    };

    gemm_lstm<<<dim3(1, 96), blk, 0, stream>>>(mkLin(hbuf0[1], predsb), gz, 0);
    copy_next<<<(BAT * FEAT) / 256, 256, 0, stream>>>(predsb, out + OUT_NEXT);

    for (int n = 1; n < NPRED; ++n) {
        u16* cur0 = (n & 1) ? hbuf0[0] : hbuf1[0];
        u16* cur1 = (n & 1) ? hbuf0[1] : hbuf1[1];
        u16* nxt0 = (n & 1) ? hbuf1[0] : hbuf0[0];
        u16* nxt1 = (n & 1) ? hbuf1[1] : hbuf0[1];
        const u16* pin = predsb + (size_t)(n - 1) * MB * FEAT;
        u16* pout = predsb + (size_t)n * MB * FEAT;
        gemm_lstm<<<dim3(32, 96), blk, 0, stream>>>(mkB(0, pin, 1, cur0, nxt0), gz, 0);
        gemm_lstm<<<dim3(32, 96), blk, 0, stream>>>(mkB(1, nxt0, 2, cur1, nxt1), gz, 0);
        gemm_lstm<<<dim3(1, 96), blk, 0, stream>>>(mkLin(nxt1, pout), gz, 0);
    }

    gather_out<<<(NSAMP * BAT * FEAT * NPRED) / 256, 256, 0, stream>>>(inMusic, predsb, out);
}

// Round 5
// 56950.165 us; speedup vs baseline: 1.6172x; 1.1314x over previous
//
#include <hip/hip_runtime.h>

#define HID 1024
#define FEAT 128
#define BAT 128
#define NSAMP 96
#define NPRED 8
#define GD 4096                    // 4*HID
#define MB (NSAMP * BAT)           // 12288
#define SLOTE ((size_t)BAT * HID)  // 131072 elements per 128-row state slot

typedef unsigned short u16;
typedef short bf16x8 __attribute__((ext_vector_type(8)));
typedef float f32x4 __attribute__((ext_vector_type(4)));

__device__ inline u16 f2bf(float f) {
    unsigned u = __float_as_uint(f);
    u += 0x7FFFu + ((u >> 16) & 1u);
    return (u16)(u >> 16);
}
__device__ inline float bf2f(u16 h) { return __uint_as_float(((unsigned)h) << 16); }
__device__ inline float fsig(float x) { return 1.0f / (1.0f + __expf(-x)); }
__device__ inline float ftanh(float x) { return 1.0f - 2.0f / (__expf(2.0f * x) + 1.0f); }

#define LDSS 40  // LDS panel row stride in shorts (32 + 8 pad)

// Slot-panel state layout: slot [128 rows][1024 units] stored as
// [32 panels][128 rows][32 units]; block tn owns panel tn exclusively.

union SMem {
    struct { u16 a[2][128 * LDSS]; u16 b[2][128 * LDSS]; } st;
    float g[32][132];
};

// ---- device-scope flag sync (cross-XCD, G16 pattern) ----
__device__ inline void wait_ge32(int* f) {
    if (threadIdx.x == 0) {
        long t = 0;
        while (__hip_atomic_load(f, __ATOMIC_ACQUIRE, __HIP_MEMORY_SCOPE_AGENT) < 32) {
            __builtin_amdgcn_s_sleep(2);
            if (++t > 2000000L) break;   // fail (wrong answer) rather than hang
        }
    }
    __syncthreads();
}
__device__ inline void signal_inc(int* f) {
    __threadfence();
    __syncthreads();
    if (threadIdx.x == 0)
        __hip_atomic_fetch_add(f, 1, __ATOMIC_RELEASE, __HIP_MEMORY_SCOPE_AGENT);
}

// =====================================================================
// Phase A: persistent 2-layer LSTM filter chain. 64 blocks: b<32 -> L0
// panel b; b>=32 -> L1 panel b-32. c-state in registers across 96 steps.
// =====================================================================
__global__ __launch_bounds__(256, 1) void lstm_chain(
    const float* __restrict__ inMusic,
    const u16* __restrict__ Wih0p, const u16* __restrict__ Whh0p,
    const u16* __restrict__ Wih1p, const u16* __restrict__ Whh1p,
    const float* __restrict__ bp0, const float* __restrict__ bp1,
    const float* __restrict__ c0,
    u16* __restrict__ chainH, u16* __restrict__ chainCb,
    float* __restrict__ h_std, float* __restrict__ c_std,
    int* __restrict__ flags)
{
    __shared__ SMem sm;
    const int blk = blockIdx.x;
    const int l = blk >> 5, tn = blk & 31;
    const int tid = threadIdx.x;
    const int wave = tid >> 6, lane = tid & 63;
    const int wm = wave >> 1, wn = wave & 1;
    const int quad = lane >> 4, lc = lane & 15;
    const int rl = tid >> 3, ub = (tid & 7) * 4;
    const int br = tid >> 2, bc = (tid & 3) * 8;

    const u16* BihS = (l ? Wih1p : Wih0p) + (size_t)tn * 128 * (l ? HID : FEAT);
    const u16* BhhS = (l ? Whh1p : Whh0p) + (size_t)tn * 128 * HID;
    const float* bias = l ? bp1 : bp0;
    int* fl0 = flags;
    int* fl1 = flags + 97;

    // c filter state in registers: creg[i][uu] <-> (row lrow(i), unit tn*32+ub+uu)
    float creg[4][4];
#pragma unroll
    for (int i = 0; i < 4; ++i) {
        int lrow = (rl >> 4) * 64 + i * 16 + (rl & 15);
        float4 c4 = *(const float4*)(c0 + (size_t)l * SLOTE + (size_t)lrow * HID + tn * 32 + ub);
        creg[i][0] = c4.x; creg[i][1] = c4.y; creg[i][2] = c4.z; creg[i][3] = c4.w;
    }
    float bv[4];
#pragma unroll
    for (int j = 0; j < 4; ++j) bv[j] = bias[tn * 128 + wn * 64 + j * 16 + lc];

    for (int k = 0; k < NSAMP; ++k) {
        const int rk = (k <= 1) ? 0 : k;
        if (l == 0) { wait_ge32(fl0 + rk); }
        else       { wait_ge32(fl0 + k + 1); wait_ge32(fl1 + rk); }

        f32x4 acc[4][4];
#pragma unroll
        for (int j = 0; j < 4; ++j) {
            f32x4 bvv = {bv[j], bv[j], bv[j], bv[j]};
#pragma unroll
            for (int i = 0; i < 4; ++i) acc[i][j] = bvv;
        }

        auto mfma_panels = [&]() {
#pragma unroll
            for (int p = 0; p < 2; ++p) {
                bf16x8 aF[4], bF[4];
#pragma unroll
                for (int i = 0; i < 4; ++i)
                    aF[i] = *(const bf16x8*)&sm.st.a[p][(wm * 64 + i * 16 + lc) * LDSS + quad * 8];
#pragma unroll
                for (int j = 0; j < 4; ++j)
                    bF[j] = *(const bf16x8*)&sm.st.b[p][(wn * 64 + j * 16 + lc) * LDSS + quad * 8];
#pragma unroll
                for (int i = 0; i < 4; ++i)
#pragma unroll
                    for (int j = 0; j < 4; ++j)
                        acc[i][j] = __builtin_amdgcn_mfma_f32_16x16x32_bf16(aF[i], bF[j], acc[i][j], 0, 0, 0);
            }
        };

        // slot-panel bf16 A, K=1024
        auto kloop_sp = [&](const u16* Ab, const u16* Bb) {
            auto ao = [&](int row, int k0, int h) -> size_t {
                return ((size_t)((k0 >> 5) + h) * 128 + row) * 32 + bc;
            };
            uint4 aR[2][2], bR[2][2];
#pragma unroll
            for (int it = 0; it < 2; ++it)
#pragma unroll
                for (int h = 0; h < 2; ++h) {
                    aR[it][h] = *(const uint4*)(Ab + ao(it * 64 + br, 0, h));
                    bR[it][h] = *(const uint4*)(Bb + (size_t)(it * 64 + br) * HID + bc + h * 32);
                }
            for (int ii = 0; ii < 16; ++ii) {
                __syncthreads();
#pragma unroll
                for (int it = 0; it < 2; ++it)
#pragma unroll
                    for (int h = 0; h < 2; ++h) {
                        *(uint4*)&sm.st.a[h][(it * 64 + br) * LDSS + bc] = aR[it][h];
                        *(uint4*)&sm.st.b[h][(it * 64 + br) * LDSS + bc] = bR[it][h];
                    }
                if (ii + 1 < 16) {
                    int k0 = (ii + 1) * 64;
#pragma unroll
                    for (int it = 0; it < 2; ++it)
#pragma unroll
                        for (int h = 0; h < 2; ++h) {
                            aR[it][h] = *(const uint4*)(Ab + ao(it * 64 + br, k0, h));
                            bR[it][h] = *(const uint4*)(Bb + (size_t)(it * 64 + br) * HID + k0 + bc + h * 32);
                        }
                }
                __syncthreads();
                mfma_panels();
            }
        };

        if (l == 0) {
            // seg0: x(k) f32 [128][128], K=128 (2 iters)
            const float* Af = inMusic + (size_t)k * BAT * FEAT;
            const int ar = tid >> 4, ac = (tid & 15) * 4;
            const int apan = ac >> 5, alc = ac & 31;
            float4 aR[8]; uint4 bR[2][2];
#pragma unroll
            for (int it = 0; it < 8; ++it)
                aR[it] = *(const float4*)(Af + (size_t)(it * 16 + ar) * FEAT + ac);
#pragma unroll
            for (int it = 0; it < 2; ++it)
#pragma unroll
                for (int h = 0; h < 2; ++h)
                    bR[it][h] = *(const uint4*)(BihS + (size_t)(it * 64 + br) * FEAT + bc + h * 32);
            for (int ii = 0; ii < 2; ++ii) {
                __syncthreads();
#pragma unroll
                for (int it = 0; it < 8; ++it) {
                    ushort4 pk = make_ushort4(f2bf(aR[it].x), f2bf(aR[it].y),
                                              f2bf(aR[it].z), f2bf(aR[it].w));
                    *(ushort4*)&sm.st.a[apan][(it * 16 + ar) * LDSS + alc] = pk;
                }
#pragma unroll
                for (int it = 0; it < 2; ++it)
#pragma unroll
                    for (int h = 0; h < 2; ++h)
                        *(uint4*)&sm.st.b[h][(it * 64 + br) * LDSS + bc] = bR[it][h];
                if (ii == 0) {
#pragma unroll
                    for (int it = 0; it < 8; ++it)
                        aR[it] = *(const float4*)(Af + (size_t)(it * 16 + ar) * FEAT + ac + 64);
#pragma unroll
                    for (int it = 0; it < 2; ++it)
#pragma unroll
                        for (int h = 0; h < 2; ++h)
                            bR[it][h] = *(const uint4*)(BihS + (size_t)(it * 64 + br) * FEAT + 64 + bc + h * 32);
                }
                __syncthreads();
                mfma_panels();
            }
            kloop_sp(chainH + (size_t)rk * SLOTE, BhhS);
        } else {
            kloop_sp(chainH + (size_t)(k + 1) * SLOTE, BihS);              // h0(k+1)
            kloop_sp(chainH + (size_t)(97 + rk) * SLOTE, BhhS);            // h1(rk)
        }

        // ---- epilogue: gates -> (h,c); c in registers; commit only if k>=1
        __syncthreads();   // sG aliases staging panels
        size_t slotBase = (size_t)(l * 97 + k + 1) * SLOTE;
#pragma unroll 1
        for (int i = 0; i < 4; ++i) {
#pragma unroll
            for (int j = 0; j < 4; ++j)
#pragma unroll
                for (int r = 0; r < 4; ++r)
                    sm.g[wm * 16 + quad * 4 + r][wn * 64 + j * 16 + lc] = acc[i][j][r];
            __syncthreads();
            int lrow = (rl >> 4) * 64 + i * 16 + (rl & 15);
            size_t pOff = slotBase + ((size_t)tn * 128 + lrow) * 32 + ub;
            float c2v[4], h2v[4];
#pragma unroll
            for (int uu = 0; uu < 4; ++uu) {
                float4 gg = *(const float4*)&sm.g[rl][(ub + uu) * 4];
                float iv = fsig(gg.x), fv = fsig(gg.y), gv = ftanh(gg.z), ov = fsig(gg.w);
                float c2 = fv * creg[i][uu] + iv * gv;
                if (k != 0) creg[i][uu] = c2;    // k=0 result not committed (upd = k>=1)
                c2v[uu] = c2;
                h2v[uu] = ov * ftanh(c2);
            }
            *(ushort4*)(chainH + pOff) =
                make_ushort4(f2bf(h2v[0]), f2bf(h2v[1]), f2bf(h2v[2]), f2bf(h2v[3]));
            *(ushort4*)(chainCb + pOff) =
                make_ushort4(f2bf(c2v[0]), f2bf(c2v[1]), f2bf(c2v[2]), f2bf(c2v[3]));
            if (k == 95) {
                size_t sOff = (size_t)l * SLOTE + (size_t)lrow * HID + tn * 32 + ub;
                *(float4*)(h_std + sOff) = make_float4(h2v[0], h2v[1], h2v[2], h2v[3]);
                *(float4*)(c_std + sOff) = make_float4(c2v[0], c2v[1], c2v[2], c2v[3]);
            }
            __syncthreads();
        }
        signal_inc((l == 0 ? fl0 : fl1) + k + 1);
    }
}

// =====================================================================
// Phase B: batched GEMM+LSTM epilogue. pers=1: 512 blocks, tn=bx&31
// (XCD-pinned weight stripe), 6 tm tiles each. pers=0: grid (x=tn, y=tm).
// =====================================================================
struct GArgs {
    const void* A1;                // aL1: 1 = bf16 row-major, 2 = bf16 slot-panel
    const u16* A2;                 // slot-panel (or null if K2=0)
    const u16 *B1, *B2;            // row-major [4096][K]
    const float* bias;
    const u16* c_in; u16* cout_b;  // slot-panel bf16
    u16* h_out;                    // slot-panel bf16
    u16* lin_out;                  // mode 1: row-major [M][128] bf16
    int aL1, lda1, K1, K2, mode;
};

__global__ __launch_bounds__(256, 2) void gemm_lstm(GArgs g, int pers)
{
    __shared__ SMem sm;
    const int tid = threadIdx.x;
    const int wave = tid >> 6, lane = tid & 63;
    const int wm = wave >> 1, wn = wave & 1;
    const int quad = lane >> 4, lc = lane & 15;
    const int br = tid >> 2, bc = (tid & 3) * 8;
    const int nt = pers ? 6 : 1;
    const int tn = pers ? (blockIdx.x & 31) : blockIdx.x;
    const int tm0 = pers ? ((blockIdx.x >> 5) * 6) : blockIdx.y;

    for (int t = 0; t < nt; ++t) {
        const int tm = tm0 + t;
        f32x4 acc[4][4];
#pragma unroll
        for (int j = 0; j < 4; ++j) {
            float bvx = g.bias[tn * 128 + wn * 64 + j * 16 + lc];
            f32x4 bvv = {bvx, bvx, bvx, bvx};
#pragma unroll
            for (int i = 0; i < 4; ++i) acc[i][j] = bvv;
        }

        auto mfma_panels = [&]() {
#pragma unroll
            for (int p = 0; p < 2; ++p) {
                bf16x8 aF[4], bF[4];
#pragma unroll
                for (int i = 0; i < 4; ++i)
                    aF[i] = *(const bf16x8*)&sm.st.a[p][(wm * 64 + i * 16 + lc) * LDSS + quad * 8];
#pragma unroll
                for (int j = 0; j < 4; ++j)
                    bF[j] = *(const bf16x8*)&sm.st.b[p][(wn * 64 + j * 16 + lc) * LDSS + quad * 8];
#pragma unroll
                for (int i = 0; i < 4; ++i)
#pragma unroll
                    for (int j = 0; j < 4; ++j)
                        acc[i][j] = __builtin_amdgcn_mfma_f32_16x16x32_bf16(aF[i], bF[j], acc[i][j], 0, 0, 0);
            }
        };

        for (int seg = 0; seg < 2; ++seg) {
            const int K = seg ? g.K2 : g.K1;
            if (K == 0) continue;
            const int aL = seg ? 2 : g.aL1;
            const int lda = g.lda1;
            const u16* Ab = seg ? (g.A2 + (size_t)tm * SLOTE)
                                : ((const u16*)g.A1 +
                                   (aL == 2 ? (size_t)tm * SLOTE : (size_t)tm * 128 * lda));
            const u16* Bb = (seg ? g.B2 : g.B1) + (size_t)tn * 128 * K;
            const int NIT = K >> 6;
            auto ao = [&](int row, int k0, int h) -> size_t {
                return aL == 2 ? ((size_t)((k0 >> 5) + h) * 128 + row) * 32 + bc
                               : (size_t)row * lda + k0 + h * 32 + bc;
            };
            uint4 aR[2][2], bR[2][2];
#pragma unroll
            for (int it = 0; it < 2; ++it)
#pragma unroll
                for (int h = 0; h < 2; ++h) {
                    aR[it][h] = *(const uint4*)(Ab + ao(it * 64 + br, 0, h));
                    bR[it][h] = *(const uint4*)(Bb + (size_t)(it * 64 + br) * K + bc + h * 32);
                }
            for (int ii = 0; ii < NIT; ++ii) {
                __syncthreads();
#pragma unroll
                for (int it = 0; it < 2; ++it)
#pragma unroll
                    for (int h = 0; h < 2; ++h) {
                        *(uint4*)&sm.st.a[h][(it * 64 + br) * LDSS + bc] = aR[it][h];
                        *(uint4*)&sm.st.b[h][(it * 64 + br) * LDSS + bc] = bR[it][h];
                    }
                if (ii + 1 < NIT) {
                    int k0 = (ii + 1) * 64;
#pragma unroll
                    for (int it = 0; it < 2; ++it)
#pragma unroll
                        for (int h = 0; h < 2; ++h) {
                            aR[it][h] = *(const uint4*)(Ab + ao(it * 64 + br, k0, h));
                            bR[it][h] = *(const uint4*)(Bb + (size_t)(it * 64 + br) * K + k0 + bc + h * 32);
                        }
                }
                __syncthreads();
                mfma_panels();
            }
        }

        if (g.mode == 0) {
            __syncthreads();   // sG aliases staging panels
            const int rl = tid >> 3, ub = (tid & 7) * 4;
#pragma unroll 1
            for (int i = 0; i < 4; ++i) {
#pragma unroll
                for (int j = 0; j < 4; ++j)
#pragma unroll
                    for (int r = 0; r < 4; ++r)
                        sm.g[wm * 16 + quad * 4 + r][wn * 64 + j * 16 + lc] = acc[i][j][r];
                __syncthreads();
                int lrow = (rl >> 4) * 64 + i * 16 + (rl & 15);
                size_t pOff = (size_t)tm * SLOTE + ((size_t)tn * 128 + lrow) * 32 + ub;
                ushort4 co = *(const ushort4*)(g.c_in + pOff);
                float cold[4] = {bf2f(co.x), bf2f(co.y), bf2f(co.z), bf2f(co.w)};
                float c2v[4], h2v[4];
#pragma unroll
                for (int uu = 0; uu < 4; ++uu) {
                    float4 gg = *(const float4*)&sm.g[rl][(ub + uu) * 4];
                    float iv = fsig(gg.x), fv = fsig(gg.y), gv = ftanh(gg.z), ov = fsig(gg.w);
                    float c2 = fv * cold[uu] + iv * gv;
                    c2v[uu] = c2;
                    h2v[uu] = ov * ftanh(c2);
                }
                *(ushort4*)(g.cout_b + pOff) =
                    make_ushort4(f2bf(c2v[0]), f2bf(c2v[1]), f2bf(c2v[2]), f2bf(c2v[3]));
                *(ushort4*)(g.h_out + pOff) =
                    make_ushort4(f2bf(h2v[0]), f2bf(h2v[1]), f2bf(h2v[2]), f2bf(h2v[3]));
                __syncthreads();
            }
        } else {
#pragma unroll
            for (int i = 0; i < 4; ++i)
#pragma unroll
                for (int j = 0; j < 4; ++j)
#pragma unroll
                    for (int r = 0; r < 4; ++r) {
                        int grow = tm * 128 + wm * 64 + i * 16 + quad * 4 + r;
                        int gcol = tn * 128 + wn * 64 + j * 16 + lc;
                        g.lin_out[(size_t)grow * FEAT + gcol] = f2bf(acc[i][j][r]);
                    }
        }
    }
}

// ---- setup / epilogue kernels ----
__global__ void convert_weight(const float* __restrict__ src, u16* __restrict__ dst,
                               int kshift, int permute) {
    int idx = blockIdx.x * 256 + threadIdx.x;
    int row = idx >> kshift;
    int k = idx & ((1 << kshift) - 1);
    int srow = permute ? ((row & 3) * HID + (row >> 2)) : row;
    dst[idx] = f2bf(src[((size_t)srow << kshift) | k]);
}

__global__ void combine_bias(const float* __restrict__ bi, const float* __restrict__ bh,
                             float* __restrict__ dst) {
    int j = blockIdx.x * 256 + threadIdx.x;  // 4096
    int s = (j & 3) * HID + (j >> 2);
    dst[j] = bi[s] + bh[s];
}

__global__ void init_state(const float* __restrict__ h0, u16* __restrict__ chainH) {
    int idx = blockIdx.x * 256 + threadIdx.x;  // 2*BAT*HID
    int l = idx >> 17;
    int r = idx & (int)(SLOTE - 1);
    int b = r >> 10, hh = r & 1023;
    size_t po = ((size_t)(hh >> 5) * 128 + b) * 32 + (hh & 31);
    chainH[(size_t)l * 97 * SLOTE + po] = f2bf(h0[idx]);
}

__global__ void zero_flags(int* __restrict__ f) {
    int i = threadIdx.x;
    if (i < 194) f[i] = (i == 0 || i == 97) ? 32 : 0;
}

__global__ void copy_next(const u16* __restrict__ predsb, float* __restrict__ out) {
    int idx = blockIdx.x * 256 + threadIdx.x;  // BAT*FEAT
    out[idx] = bf2f(predsb[(size_t)95 * BAT * FEAT + idx]);
}

__global__ void gather_out(const float* __restrict__ inMusic, const u16* __restrict__ predsb,
                           float* __restrict__ outM) {
    int idx = blockIdx.x * 256 + threadIdx.x;  // 96*128*128*8
    int n = idx & 7;
    int f = (idx >> 3) & 127;
    int b = (idx >> 10) & 127;
    int r = idx >> 17;
    float v = 0.0f;
    if (r < NPRED && n >= r) {
        v = inMusic[((size_t)r * BAT + b) * FEAT + f];
    } else {
        int k = r - n - 1;
        if (n < k) v = bf2f(predsb[((size_t)n * MB + (size_t)k * BAT + b) * FEAT + f]);
    }
    outM[idx] = v;
}

__global__ void zero_out(float* __restrict__ o, int nmax) {
    int idx = blockIdx.x * 256 + threadIdx.x;
    if (idx < nmax) o[idx] = 0.0f;
}

extern "C" void kernel_launch(void* const* d_in, const int* in_sizes, int n_in,
                              void* d_out, int out_size, void* d_ws, size_t ws_size,
                              hipStream_t stream) {
    (void)in_sizes; (void)n_in;
    const float* inMusic = (const float*)d_in[0];
    const float* h0   = (const float*)d_in[1];
    const float* c0   = (const float*)d_in[2];
    const float* Wih0 = (const float*)d_in[3];
    const float* Whh0 = (const float*)d_in[4];
    const float* bih0 = (const float*)d_in[5];
    const float* bhh0 = (const float*)d_in[6];
    const float* Wih1 = (const float*)d_in[7];
    const float* Whh1 = (const float*)d_in[8];
    const float* bih1 = (const float*)d_in[9];
    const float* bhh1 = (const float*)d_in[10];
    const float* Wlin = (const float*)d_in[11];
    const float* blin = (const float*)d_in[12];
    float* out = (float*)d_out;

    const size_t OUT_H = (size_t)NSAMP * BAT * FEAT * NPRED;  // 12582912
    const size_t OUT_C = OUT_H + 2 * SLOTE;
    const size_t OUT_NEXT = OUT_C + 2 * SLOTE;

    char* ws = (char*)d_ws;
    size_t off = 0;
    auto alloc = [&](size_t bytes) {
        void* p = ws + off;
        off = (off + bytes + 255) & ~(size_t)255;
        return p;
    };
    u16* Wih0p = (u16*)alloc((size_t)GD * FEAT * 2);
    u16* Whh0p = (u16*)alloc((size_t)GD * HID * 2);
    u16* Wih1p = (u16*)alloc((size_t)GD * HID * 2);
    u16* Whh1p = (u16*)alloc((size_t)GD * HID * 2);
    u16* Wlinb = (u16*)alloc((size_t)FEAT * HID * 2);
    float* bp0 = (float*)alloc(GD * 4);
    float* bp1 = (float*)alloc(GD * 4);
    u16* chainH  = (u16*)alloc((size_t)2 * 97 * SLOTE * 2);  // slot-panel h slots 0..96
    u16* chainCb = (u16*)alloc((size_t)2 * 97 * SLOTE * 2);  // slot-panel c snapshots
    u16* hp2 = (u16*)alloc((size_t)2 * (size_t)NSAMP * SLOTE * 2);
    u16* predsb = (u16*)alloc((size_t)NPRED * MB * FEAT * 2);
    int* flags = (int*)alloc(256 * 4);

    if (off > ws_size) {
        zero_out<<<(out_size + 255) / 256, 256, 0, stream>>>(out, out_size);
        return;
    }

    convert_weight<<<(GD * FEAT) / 256, 256, 0, stream>>>(Wih0, Wih0p, 7, 1);
    convert_weight<<<(GD * HID) / 256, 256, 0, stream>>>(Whh0, Whh0p, 10, 1);
    convert_weight<<<(GD * HID) / 256, 256, 0, stream>>>(Wih1, Wih1p, 10, 1);
    convert_weight<<<(GD * HID) / 256, 256, 0, stream>>>(Whh1, Whh1p, 10, 1);
    convert_weight<<<(FEAT * HID) / 256, 256, 0, stream>>>(Wlin, Wlinb, 10, 0);
    combine_bias<<<GD / 256, 256, 0, stream>>>(bih0, bhh0, bp0);
    combine_bias<<<GD / 256, 256, 0, stream>>>(bih1, bhh1, bp1);
    init_state<<<(int)(2 * SLOTE) / 256, 256, 0, stream>>>(h0, chainH);
    zero_flags<<<1, 256, 0, stream>>>(flags);

    // ---- Phase A: one persistent dispatch (64 blocks <= 256 CUs)
    lstm_chain<<<64, 256, 0, stream>>>(
        inMusic, Wih0p, Whh0p, Wih1p, Whh1p, bp0, bp1, c0,
        chainH, chainCb, out + OUT_H, out + OUT_C, flags);

    auto Hs = [&](int l, int s) { return chainH + ((size_t)l * 97 + s) * SLOTE; };
    auto Cs = [&](int l, int s) { return chainCb + ((size_t)l * 97 + s) * SLOTE; };

    // ---- Phase B: 96 chains batched. h ping-pong, bf16 c in place.
    u16* hbuf0[2] = {Hs(0, 1), Hs(1, 1)};
    u16* hbuf1[2] = {hp2, hp2 + (size_t)NSAMP * SLOTE};
    u16* cB[2] = {Cs(0, 1), Cs(1, 1)};

    auto mkLin = [&](const u16* src, u16* dst) {
        GArgs a = {};
        a.A1 = src; a.aL1 = 2; a.lda1 = 0; a.K1 = HID; a.K2 = 0;
        a.B1 = Wlinb; a.bias = blin;
        a.lin_out = dst; a.mode = 1;
        return a;
    };
    auto mkB = [&](int l, const void* A1, int aL1, const u16* A2, u16* nxt) {
        GArgs a = {};
        a.A1 = A1; a.aL1 = aL1; a.lda1 = (aL1 == 1) ? FEAT : 0;
        a.K1 = (aL1 == 1) ? FEAT : HID;
        a.A2 = A2; a.K2 = HID;
        a.B1 = (l == 0) ? Wih0p : Wih1p; a.B2 = (l == 0) ? Whh0p : Whh1p;
        a.bias = (l == 0) ? bp0 : bp1;
        a.c_in = cB[l]; a.cout_b = cB[l];
        a.h_out = nxt; a.mode = 0;
        return a;
    };

    gemm_lstm<<<dim3(1, 96), 256, 0, stream>>>(mkLin(hbuf0[1], predsb), 0);
    copy_next<<<(BAT * FEAT) / 256, 256, 0, stream>>>(predsb, out + OUT_NEXT);

    for (int n = 1; n < NPRED; ++n) {
        u16* cur0 = (n & 1) ? hbuf0[0] : hbuf1[0];
        u16* cur1 = (n & 1) ? hbuf0[1] : hbuf1[1];
        u16* nxt0 = (n & 1) ? hbuf1[0] : hbuf0[0];
        u16* nxt1 = (n & 1) ? hbuf1[1] : hbuf0[1];
        const u16* pin = predsb + (size_t)(n - 1) * MB * FEAT;
        u16* pout = predsb + (size_t)n * MB * FEAT;
        gemm_lstm<<<512, 256, 0, stream>>>(mkB(0, pin, 1, cur0, nxt0), 1);
        gemm_lstm<<<512, 256, 0, stream>>>(mkB(1, nxt0, 2, cur1, nxt1), 1);
        gemm_lstm<<<dim3(1, 96), 256, 0, stream>>>(mkLin(nxt1, pout), 0);
    }

    gather_out<<<(NSAMP * BAT * FEAT * NPRED) / 256, 256, 0, stream>>>(inMusic, predsb, out);
}

// Round 6
// 36675.247 us; speedup vs baseline: 2.5112x; 1.5528x over previous
//
#include <hip/hip_runtime.h>

#define HID 1024
#define FEAT 128
#define BAT 128
#define NSAMP 96
#define NPRED 8
#define GD 4096                    // 4*HID
#define MB (NSAMP * BAT)           // 12288
#define SLOTE ((size_t)BAT * HID)  // 131072 elements per 128-row state slot
#define PREDT 16384                // elements per pred tile (4 panels)

typedef unsigned short u16;
typedef unsigned int u32;
typedef short bf16x8 __attribute__((ext_vector_type(8)));
typedef float f32x4 __attribute__((ext_vector_type(4)));

__device__ inline u16 f2bf(float f) {
    unsigned u = __float_as_uint(f);
    u += 0x7FFFu + ((u >> 16) & 1u);
    return (u16)(u >> 16);
}
__device__ inline float bf2f(u16 h) { return __uint_as_float(((unsigned)h) << 16); }
__device__ inline float fsig(float x) { return 1.0f / (1.0f + __expf(-x)); }
__device__ inline float ftanh(float x) { return 1.0f - 2.0f / (__expf(2.0f * x) + 1.0f); }

// Panel-major layout everywhere: a [R rows][K] matrix is stored as
// [K/32 panels][R=128 rows][32 k] bf16; each panel = 8 KB contiguous.
// States: slot-panel (panel = unit-chunk). Weights: per-output-stripe panels.

__device__ inline void gl2lds16(const u16* g, u16* l) {
    __builtin_amdgcn_global_load_lds(
        (const __attribute__((address_space(1))) u32*)g,
        (__attribute__((address_space(3))) u32*)l, 16, 0, 0);
}

// ---- per-block flags: word (l,step,b) at ((l*97+step)*32+b)*32 ints ----
#define FLAGN (2 * 97 * 32 * 32)
__device__ inline void waitset(const int* base) {
    const int tid = threadIdx.x;
    if (tid < 64) {
        long t = 0;
        for (;;) {
            int v = (tid < 32)
                ? __hip_atomic_load(base + tid * 32, __ATOMIC_RELAXED, __HIP_MEMORY_SCOPE_AGENT)
                : 1;
            if (__all(v != 0)) break;
            __builtin_amdgcn_s_sleep(2);
            if (++t > 3000000L) break;   // bounded: fail loud (wrong answer), not hang
        }
    }
    __builtin_amdgcn_fence(__ATOMIC_ACQUIRE, "agent");
    __syncthreads();
}

#define LDSS 40  // phase-A padded LDS row stride (shorts)

union SMemA {
    struct { u16 a[2][128 * LDSS]; u16 b[2][128 * LDSS]; } st;
    float g[32][132];
};

// =====================================================================
// Phase A: persistent 2-layer filter chain. 64 blocks: b<32 -> L0 panel
// b; b>=32 -> L1. c in registers. Per-block flags, 1 acquire fence/step.
// =====================================================================
__global__ __launch_bounds__(256, 1) void lstm_chain(
    const float* __restrict__ inMusic,
    const u16* __restrict__ Wih0p, const u16* __restrict__ Whh0p,
    const u16* __restrict__ Wih1p, const u16* __restrict__ Whh1p,
    const float* __restrict__ bp0, const float* __restrict__ bp1,
    const float* __restrict__ c0,
    u16* __restrict__ chainH, u16* __restrict__ chainCb,
    float* __restrict__ h_std, float* __restrict__ c_std,
    int* __restrict__ flags)
{
    __shared__ SMemA sm;
    const int blk = blockIdx.x;
    const int l = blk >> 5, tn = blk & 31;
    const int tid = threadIdx.x;
    const int wave = tid >> 6, lane = tid & 63;
    const int wm = wave >> 1, wn = wave & 1;
    const int quad = lane >> 4, lc = lane & 15;
    const int rl = tid >> 3, ub = (tid & 7) * 4;
    const int br = tid >> 2, bc = (tid & 3) * 8;

    // panel-major weight stripes
    const u16* BihS = (l ? Wih1p : Wih0p) + (size_t)tn * 128 * (l ? HID : FEAT);
    const u16* BhhS = (l ? Whh1p : Whh0p) + (size_t)tn * 128 * HID;
    const float* bias = l ? bp1 : bp0;
    auto fw = [&](int ll, int s) { return flags + ((size_t)(ll * 97 + s) * 32) * 32; };

    float creg[4][4];
#pragma unroll
    for (int i = 0; i < 4; ++i) {
        int lrow = (rl >> 4) * 64 + i * 16 + (rl & 15);
        float4 c4 = *(const float4*)(c0 + (size_t)l * SLOTE + (size_t)lrow * HID + tn * 32 + ub);
        creg[i][0] = c4.x; creg[i][1] = c4.y; creg[i][2] = c4.z; creg[i][3] = c4.w;
    }
    float bv[4];
#pragma unroll
    for (int j = 0; j < 4; ++j) bv[j] = bias[tn * 128 + wn * 64 + j * 16 + lc];

    for (int k = 0; k < NSAMP; ++k) {
        const int rk = (k <= 1) ? 0 : k;
        if (l == 0) { waitset(fw(0, rk)); }
        else       { waitset(fw(0, k + 1)); waitset(fw(1, rk)); }

        f32x4 acc[4][4];
#pragma unroll
        for (int j = 0; j < 4; ++j) {
            f32x4 bvv = {bv[j], bv[j], bv[j], bv[j]};
#pragma unroll
            for (int i = 0; i < 4; ++i) acc[i][j] = bvv;
        }

        auto mfma_panels = [&]() {
#pragma unroll
            for (int p = 0; p < 2; ++p) {
                bf16x8 aF[4], bF[4];
#pragma unroll
                for (int i = 0; i < 4; ++i)
                    aF[i] = *(const bf16x8*)&sm.st.a[p][(wm * 64 + i * 16 + lc) * LDSS + quad * 8];
#pragma unroll
                for (int j = 0; j < 4; ++j)
                    bF[j] = *(const bf16x8*)&sm.st.b[p][(wn * 64 + j * 16 + lc) * LDSS + quad * 8];
#pragma unroll
                for (int i = 0; i < 4; ++i)
#pragma unroll
                    for (int j = 0; j < 4; ++j)
                        acc[i][j] = __builtin_amdgcn_mfma_f32_16x16x32_bf16(aF[i], bF[j], acc[i][j], 0, 0, 0);
            }
        };

        // panel-major offset (same for state A and weight B)
        auto po = [&](int row, int k0, int h) -> size_t {
            return ((size_t)((k0 >> 5) + h) * 128 + row) * 32 + bc;
        };
        auto kloop_sp = [&](const u16* Ab, const u16* Bb) {
            uint4 aR[2][2], bR[2][2];
#pragma unroll
            for (int it = 0; it < 2; ++it)
#pragma unroll
                for (int h = 0; h < 2; ++h) {
                    aR[it][h] = *(const uint4*)(Ab + po(it * 64 + br, 0, h));
                    bR[it][h] = *(const uint4*)(Bb + po(it * 64 + br, 0, h));
                }
            for (int ii = 0; ii < 16; ++ii) {
                __syncthreads();
#pragma unroll
                for (int it = 0; it < 2; ++it)
#pragma unroll
                    for (int h = 0; h < 2; ++h) {
                        *(uint4*)&sm.st.a[h][(it * 64 + br) * LDSS + bc] = aR[it][h];
                        *(uint4*)&sm.st.b[h][(it * 64 + br) * LDSS + bc] = bR[it][h];
                    }
                if (ii + 1 < 16) {
                    int k0 = (ii + 1) * 64;
#pragma unroll
                    for (int it = 0; it < 2; ++it)
#pragma unroll
                        for (int h = 0; h < 2; ++h) {
                            aR[it][h] = *(const uint4*)(Ab + po(it * 64 + br, k0, h));
                            bR[it][h] = *(const uint4*)(Bb + po(it * 64 + br, k0, h));
                        }
                }
                __syncthreads();
                mfma_panels();
            }
        };

        if (l == 0) {
            const float* Af = inMusic + (size_t)k * BAT * FEAT;
            const int ar = tid >> 4, ac = (tid & 15) * 4;
            const int apan = ac >> 5, alc = ac & 31;
            float4 aR[8]; uint4 bR[2][2];
#pragma unroll
            for (int it = 0; it < 8; ++it)
                aR[it] = *(const float4*)(Af + (size_t)(it * 16 + ar) * FEAT + ac);
#pragma unroll
            for (int it = 0; it < 2; ++it)
#pragma unroll
                for (int h = 0; h < 2; ++h)
                    bR[it][h] = *(const uint4*)(BihS + po(it * 64 + br, 0, h));
            for (int ii = 0; ii < 2; ++ii) {
                __syncthreads();
#pragma unroll
                for (int it = 0; it < 8; ++it) {
                    ushort4 pk = make_ushort4(f2bf(aR[it].x), f2bf(aR[it].y),
                                              f2bf(aR[it].z), f2bf(aR[it].w));
                    *(ushort4*)&sm.st.a[apan][(it * 16 + ar) * LDSS + alc] = pk;
                }
#pragma unroll
                for (int it = 0; it < 2; ++it)
#pragma unroll
                    for (int h = 0; h < 2; ++h)
                        *(uint4*)&sm.st.b[h][(it * 64 + br) * LDSS + bc] = bR[it][h];
                if (ii == 0) {
#pragma unroll
                    for (int it = 0; it < 8; ++it)
                        aR[it] = *(const float4*)(Af + (size_t)(it * 16 + ar) * FEAT + ac + 64);
#pragma unroll
                    for (int it = 0; it < 2; ++it)
#pragma unroll
                        for (int h = 0; h < 2; ++h)
                            bR[it][h] = *(const uint4*)(BihS + po(it * 64 + br, 64, h));
                }
                __syncthreads();
                mfma_panels();
            }
            kloop_sp(chainH + (size_t)rk * SLOTE, BhhS);
        } else {
            kloop_sp(chainH + (size_t)(k + 1) * SLOTE, BihS);
            kloop_sp(chainH + (size_t)(97 + rk) * SLOTE, BhhS);
        }

        __syncthreads();   // sG aliases staging panels
        size_t slotBase = (size_t)(l * 97 + k + 1) * SLOTE;
#pragma unroll 1
        for (int i = 0; i < 4; ++i) {
#pragma unroll
            for (int j = 0; j < 4; ++j)
#pragma unroll
                for (int r = 0; r < 4; ++r)
                    sm.g[wm * 16 + quad * 4 + r][wn * 64 + j * 16 + lc] = acc[i][j][r];
            __syncthreads();
            int lrow = (rl >> 4) * 64 + i * 16 + (rl & 15);
            size_t pOff = slotBase + ((size_t)tn * 128 + lrow) * 32 + ub;
            float c2v[4], h2v[4];
#pragma unroll
            for (int uu = 0; uu < 4; ++uu) {
                float4 gg = *(const float4*)&sm.g[rl][(ub + uu) * 4];
                float iv = fsig(gg.x), fv = fsig(gg.y), gv = ftanh(gg.z), ov = fsig(gg.w);
                float c2 = fv * creg[i][uu] + iv * gv;
                if (k != 0) creg[i][uu] = c2;    // filter update only for k>=1
                c2v[uu] = c2;
                h2v[uu] = ov * ftanh(c2);
            }
            *(ushort4*)(chainH + pOff) =
                make_ushort4(f2bf(h2v[0]), f2bf(h2v[1]), f2bf(h2v[2]), f2bf(h2v[3]));
            *(ushort4*)(chainCb + pOff) =
                make_ushort4(f2bf(c2v[0]), f2bf(c2v[1]), f2bf(c2v[2]), f2bf(c2v[3]));
            if (k == 95) {
                size_t sOff = (size_t)l * SLOTE + (size_t)lrow * HID + tn * 32 + ub;
                *(float4*)(h_std + sOff) = make_float4(h2v[0], h2v[1], h2v[2], h2v[3]);
                *(float4*)(c_std + sOff) = make_float4(c2v[0], c2v[1], c2v[2], c2v[3]);
            }
            __syncthreads();
        }
        // release: all block stores drained (barrier above), then flag store
        if (tid == 0)
            __hip_atomic_store(fw(l, k + 1) + tn * 32, 1,
                               __ATOMIC_RELEASE, __HIP_MEMORY_SCOPE_AGENT);
    }
}

// =====================================================================
// Phase B: GEMM+LSTM, global_load_lds staging, all sources panel-major.
// pers=1: 768 blocks, tn=bx&31, 4 tm tiles. pers=0: grid (tn, tm).
// =====================================================================
struct GArgs {
    const u16* A1; const u16* A2;
    const u16 *B1, *B2;
    const float* bias;
    const u16* c_in; u16* cout_b;
    u16* h_out;
    u16* lin_out;
    int KP1, KP2;          // panels (K/32) per seg; 0 = absent
    int as1, as2;          // A tile stride (elements)
    int mode;
};

__global__ __launch_bounds__(256, 3) void gemm_b(GArgs g, int pers)
{
    __shared__ u16 sA[8192], sB[8192];
    __shared__ float sG[32][132];
    const int tid = threadIdx.x;
    const int wave = tid >> 6, lane = tid & 63;
    const int wm = wave >> 1, wn = wave & 1;
    const int quad = lane >> 4, lc = lane & 15;
    const int nt = pers ? 4 : 1;
    const int tn = pers ? (blockIdx.x & 31) : blockIdx.x;
    const int tm0 = pers ? ((blockIdx.x >> 5) * 4) : blockIdx.y;

    for (int t = 0; t < nt; ++t) {
        const int tm = tm0 + t;
        f32x4 acc[4][4];
#pragma unroll
        for (int j = 0; j < 4; ++j) {
            float bvx = g.bias[tn * 128 + wn * 64 + j * 16 + lc];
            f32x4 bvv = {bvx, bvx, bvx, bvx};
#pragma unroll
            for (int i = 0; i < 4; ++i) acc[i][j] = bvv;
        }

        for (int seg = 0; seg < 2; ++seg) {
            const int KP = seg ? g.KP2 : g.KP1;
            if (!KP) continue;
            const u16* Ap = seg ? (g.A2 + (size_t)tm * g.as2)
                                : (g.A1 + (size_t)tm * g.as1);
            const u16* Bp = (seg ? g.B2 : g.B1) + (size_t)tn * KP * 4096;
            const int NIT = KP >> 1;
            for (int ii = 0; ii < NIT; ++ii) {
                __syncthreads();                       // LDS free (prior reads done)
                const u16* ga = Ap + (size_t)ii * 8192;
                const u16* gb = Bp + (size_t)ii * 8192;
#pragma unroll
                for (int c4 = 0; c4 < 4; ++c4) {
                    int ch = wave * 4 + c4;            // 16 chunks x 512 elems
                    gl2lds16(ga + ch * 512 + lane * 8, &sA[ch * 512]);
                    gl2lds16(gb + ch * 512 + lane * 8, &sB[ch * 512]);
                }
                __syncthreads();                       // vmcnt(0) drain -> data ready
#pragma unroll
                for (int p = 0; p < 2; ++p) {
                    bf16x8 aF[4], bF[4];
#pragma unroll
                    for (int i = 0; i < 4; ++i)
                        aF[i] = *(const bf16x8*)&sA[p * 4096 + (wm * 64 + i * 16 + lc) * 32 + quad * 8];
#pragma unroll
                    for (int j = 0; j < 4; ++j)
                        bF[j] = *(const bf16x8*)&sB[p * 4096 + (wn * 64 + j * 16 + lc) * 32 + quad * 8];
#pragma unroll
                    for (int i = 0; i < 4; ++i)
#pragma unroll
                        for (int j = 0; j < 4; ++j)
                            acc[i][j] = __builtin_amdgcn_mfma_f32_16x16x32_bf16(aF[i], bF[j], acc[i][j], 0, 0, 0);
                }
            }
        }

        if (g.mode == 0) {
            const int rl = tid >> 3, ub = (tid & 7) * 4;
#pragma unroll 1
            for (int i = 0; i < 4; ++i) {
#pragma unroll
                for (int j = 0; j < 4; ++j)
#pragma unroll
                    for (int r = 0; r < 4; ++r)
                        sG[wm * 16 + quad * 4 + r][wn * 64 + j * 16 + lc] = acc[i][j][r];
                __syncthreads();
                int lrow = (rl >> 4) * 64 + i * 16 + (rl & 15);
                size_t pOff = (size_t)tm * SLOTE + ((size_t)tn * 128 + lrow) * 32 + ub;
                ushort4 co = *(const ushort4*)(g.c_in + pOff);
                float cold[4] = {bf2f(co.x), bf2f(co.y), bf2f(co.z), bf2f(co.w)};
                float c2v[4], h2v[4];
#pragma unroll
                for (int uu = 0; uu < 4; ++uu) {
                    float4 gg = *(const float4*)&sG[rl][(ub + uu) * 4];
                    float iv = fsig(gg.x), fv = fsig(gg.y), gv = ftanh(gg.z), ov = fsig(gg.w);
                    float c2 = fv * cold[uu] + iv * gv;
                    c2v[uu] = c2;
                    h2v[uu] = ov * ftanh(c2);
                }
                *(ushort4*)(g.cout_b + pOff) =
                    make_ushort4(f2bf(c2v[0]), f2bf(c2v[1]), f2bf(c2v[2]), f2bf(c2v[3]));
                *(ushort4*)(g.h_out + pOff) =
                    make_ushort4(f2bf(h2v[0]), f2bf(h2v[1]), f2bf(h2v[2]), f2bf(h2v[3]));
                __syncthreads();
            }
        } else {
            // lin: write pred tile in panel-major [tm][4][128][32]
#pragma unroll
            for (int i = 0; i < 4; ++i)
#pragma unroll
                for (int j = 0; j < 4; ++j)
#pragma unroll
                    for (int r = 0; r < 4; ++r) {
                        int grow = wm * 64 + i * 16 + quad * 4 + r;
                        int gcol = wn * 64 + j * 16 + lc;
                        size_t addr = (size_t)tm * PREDT + (size_t)(gcol >> 5) * 4096
                                    + (size_t)grow * 32 + (gcol & 31);
                        g.lin_out[addr] = f2bf(acc[i][j][r]);
                    }
        }
    }
}

// ---- setup / epilogue kernels ----
// panel-major weight convert; permute=1 applies gate interleave (i,f,g,o)
__global__ void convert_weight(const float* __restrict__ src, u16* __restrict__ dst,
                               int kshift, int permute, int total) {
    int idx = blockIdx.x * 256 + threadIdx.x;
    if (idx >= total) return;
    int kk = idx & 31;
    int r = (idx >> 5) & 127;
    int kp = (idx >> 12) & ((1 << (kshift - 5)) - 1);
    int stripe = idx >> (7 + kshift);
    int jp = stripe * 128 + r;
    int srow = permute ? ((jp & 3) * HID + (jp >> 2)) : jp;
    dst[idx] = f2bf(src[((size_t)srow << kshift) + kp * 32 + kk]);
}

__global__ void combine_bias(const float* __restrict__ bi, const float* __restrict__ bh,
                             float* __restrict__ dst) {
    int j = blockIdx.x * 256 + threadIdx.x;  // 4096
    int s = (j & 3) * HID + (j >> 2);
    dst[j] = bi[s] + bh[s];
}

__global__ void init_state(const float* __restrict__ h0, u16* __restrict__ chainH) {
    int idx = blockIdx.x * 256 + threadIdx.x;  // 2*BAT*HID
    int l = idx >> 17;
    int r = idx & (int)(SLOTE - 1);
    int b = r >> 10, hh = r & 1023;
    size_t po = ((size_t)(hh >> 5) * 128 + b) * 32 + (hh & 31);
    chainH[(size_t)l * 97 * SLOTE + po] = f2bf(h0[idx]);
}

__global__ void init_flags(int* __restrict__ f) {
    int gid = blockIdx.x * 256 + threadIdx.x;
    if (gid >= FLAGN) return;
    int step = (gid >> 10) % 97;             // flag word stride 32 ints; 32 blocks/step
    f[gid] = ((gid & 31) == 0 && step == 0) ? 1 : 0;
}

__global__ void copy_next(const u16* __restrict__ predsb, float* __restrict__ out) {
    int idx = blockIdx.x * 256 + threadIdx.x;  // BAT*FEAT
    int b = idx >> 7, f = idx & 127;
    out[idx] = bf2f(predsb[(size_t)95 * PREDT + (size_t)(f >> 5) * 4096 + b * 32 + (f & 31)]);
}

__global__ void gather_out(const float* __restrict__ inMusic, const u16* __restrict__ predsb,
                           float* __restrict__ outM) {
    int idx = blockIdx.x * 256 + threadIdx.x;  // 96*128*128*8
    int n = idx & 7;
    int f = (idx >> 3) & 127;
    int b = (idx >> 10) & 127;
    int r = idx >> 17;
    float v = 0.0f;
    if (r < NPRED && n >= r) {
        v = inMusic[((size_t)r * BAT + b) * FEAT + f];
    } else {
        int k = r - n - 1;
        if (n < k)
            v = bf2f(predsb[(size_t)n * NSAMP * PREDT + (size_t)k * PREDT
                            + (size_t)(f >> 5) * 4096 + b * 32 + (f & 31)]);
    }
    outM[idx] = v;
}

__global__ void zero_out(float* __restrict__ o, int nmax) {
    int idx = blockIdx.x * 256 + threadIdx.x;
    if (idx < nmax) o[idx] = 0.0f;
}

extern "C" void kernel_launch(void* const* d_in, const int* in_sizes, int n_in,
                              void* d_out, int out_size, void* d_ws, size_t ws_size,
                              hipStream_t stream) {
    (void)in_sizes; (void)n_in;
    const float* inMusic = (const float*)d_in[0];
    const float* h0   = (const float*)d_in[1];
    const float* c0   = (const float*)d_in[2];
    const float* Wih0 = (const float*)d_in[3];
    const float* Whh0 = (const float*)d_in[4];
    const float* bih0 = (const float*)d_in[5];
    const float* bhh0 = (const float*)d_in[6];
    const float* Wih1 = (const float*)d_in[7];
    const float* Whh1 = (const float*)d_in[8];
    const float* bih1 = (const float*)d_in[9];
    const float* bhh1 = (const float*)d_in[10];
    const float* Wlin = (const float*)d_in[11];
    const float* blin = (const float*)d_in[12];
    float* out = (float*)d_out;

    const size_t OUT_H = (size_t)NSAMP * BAT * FEAT * NPRED;
    const size_t OUT_C = OUT_H + 2 * SLOTE;
    const size_t OUT_NEXT = OUT_C + 2 * SLOTE;

    char* ws = (char*)d_ws;
    size_t off = 0;
    auto alloc = [&](size_t bytes) {
        void* p = ws + off;
        off = (off + bytes + 255) & ~(size_t)255;
        return p;
    };
    u16* Wih0p = (u16*)alloc((size_t)GD * FEAT * 2);
    u16* Whh0p = (u16*)alloc((size_t)GD * HID * 2);
    u16* Wih1p = (u16*)alloc((size_t)GD * HID * 2);
    u16* Whh1p = (u16*)alloc((size_t)GD * HID * 2);
    u16* Wlinb = (u16*)alloc((size_t)FEAT * HID * 2);
    float* bp0 = (float*)alloc(GD * 4);
    float* bp1 = (float*)alloc(GD * 4);
    u16* chainH  = (u16*)alloc((size_t)2 * 97 * SLOTE * 2);
    u16* chainCb = (u16*)alloc((size_t)2 * 97 * SLOTE * 2);
    u16* hp2 = (u16*)alloc((size_t)2 * (size_t)NSAMP * SLOTE * 2);
    u16* predsb = (u16*)alloc((size_t)NPRED * NSAMP * PREDT * 2);
    int* flags = (int*)alloc((size_t)FLAGN * 4);

    if (off > ws_size) {
        zero_out<<<(out_size + 255) / 256, 256, 0, stream>>>(out, out_size);
        return;
    }

    convert_weight<<<(GD * FEAT + 255) / 256, 256, 0, stream>>>(Wih0, Wih0p, 7, 1, GD * FEAT);
    convert_weight<<<(GD * HID + 255) / 256, 256, 0, stream>>>(Whh0, Whh0p, 10, 1, GD * HID);
    convert_weight<<<(GD * HID + 255) / 256, 256, 0, stream>>>(Wih1, Wih1p, 10, 1, GD * HID);
    convert_weight<<<(GD * HID + 255) / 256, 256, 0, stream>>>(Whh1, Whh1p, 10, 1, GD * HID);
    convert_weight<<<(FEAT * HID + 255) / 256, 256, 0, stream>>>(Wlin, Wlinb, 10, 0, FEAT * HID);
    combine_bias<<<GD / 256, 256, 0, stream>>>(bih0, bhh0, bp0);
    combine_bias<<<GD / 256, 256, 0, stream>>>(bih1, bhh1, bp1);
    init_state<<<(int)(2 * SLOTE) / 256, 256, 0, stream>>>(h0, chainH);
    init_flags<<<(FLAGN + 255) / 256, 256, 0, stream>>>(flags);

    lstm_chain<<<64, 256, 0, stream>>>(
        inMusic, Wih0p, Whh0p, Wih1p, Whh1p, bp0, bp1, c0,
        chainH, chainCb, out + OUT_H, out + OUT_C, flags);

    auto Hs = [&](int l, int s) { return chainH + ((size_t)l * 97 + s) * SLOTE; };
    auto Cs = [&](int l, int s) { return chainCb + ((size_t)l * 97 + s) * SLOTE; };

    u16* hbuf0[2] = {Hs(0, 1), Hs(1, 1)};
    u16* hbuf1[2] = {hp2, hp2 + (size_t)NSAMP * SLOTE};
    u16* cB[2] = {Cs(0, 1), Cs(1, 1)};

    auto mkLin = [&](const u16* src, u16* dst) {
        GArgs a = {};
        a.A1 = src; a.KP1 = 32; a.as1 = (int)SLOTE; a.KP2 = 0;
        a.B1 = Wlinb; a.bias = blin;
        a.lin_out = dst; a.mode = 1;
        return a;
    };
    auto mkB = [&](int l, const u16* A1, int kp1, int as1, const u16* A2, u16* nxt) {
        GArgs a = {};
        a.A1 = A1; a.KP1 = kp1; a.as1 = as1;
        a.A2 = A2; a.KP2 = 32; a.as2 = (int)SLOTE;
        a.B1 = (l == 0) ? Wih0p : Wih1p; a.B2 = (l == 0) ? Whh0p : Whh1p;
        a.bias = (l == 0) ? bp0 : bp1;
        a.c_in = cB[l]; a.cout_b = cB[l];
        a.h_out = nxt; a.mode = 0;
        return a;
    };

    gemm_b<<<dim3(1, 96), 256, 0, stream>>>(mkLin(hbuf0[1], predsb), 0);
    copy_next<<<(BAT * FEAT) / 256, 256, 0, stream>>>(predsb, out + OUT_NEXT);

    for (int n = 1; n < NPRED; ++n) {
        u16* cur0 = (n & 1) ? hbuf0[0] : hbuf1[0];
        u16* cur1 = (n & 1) ? hbuf0[1] : hbuf1[1];
        u16* nxt0 = (n & 1) ? hbuf1[0] : hbuf0[0];
        u16* nxt1 = (n & 1) ? hbuf1[1] : hbuf0[1];
        const u16* pin = predsb + (size_t)(n - 1) * NSAMP * PREDT;
        u16* pout = predsb + (size_t)n * NSAMP * PREDT;
        gemm_b<<<768, 256, 0, stream>>>(mkB(0, pin, 4, PREDT, cur0, nxt0), 1);
        gemm_b<<<768, 256, 0, stream>>>(mkB(1, nxt0, 32, (int)SLOTE, cur1, nxt1), 1);
        gemm_b<<<dim3(1, 96), 256, 0, stream>>>(mkLin(nxt1, pout), 0);
    }

    gather_out<<<(NSAMP * BAT * FEAT * NPRED) / 256, 256, 0, stream>>>(inMusic, predsb, out);
}